// Round 5
// baseline (598.709 us; speedup 1.0000x reference)
//
#include <hip/hip_runtime.h>

// NystromAttention on MI355X. fp32 I/O, bf16 MFMA for the two big attention
// matmuls (k3v flash + k1x), fp32 elsewhere. Newton chain fp32, 24 launches,
// register-blocked 4x8 per thread (VALU-bound; old 2x4 shape was LDS-bound).

typedef unsigned int uint_t;
typedef unsigned short ushort_t;
typedef short s16x8 __attribute__((ext_vector_type(8)));
typedef float f32x4 __attribute__((ext_vector_type(4)));

#define NB 4
#define NH 12
#define BH 48
#define SQ 4096
#define HD 64
#define NL 128
#define SEG 32
#define SCALE 0.35355339059327379f
#define NEGBIG 1.0e9f

__device__ __forceinline__ ushort_t f2bf(float f) {
    uint_t u = __float_as_uint(f);
    u += 0x7FFFu + ((u >> 16) & 1u);   // RNE
    return (ushort_t)(u >> 16);
}
__device__ __forceinline__ uint_t pack2(float a, float b) {
    return (uint_t)f2bf(a) | ((uint_t)f2bf(b) << 16);
}
__device__ __forceinline__ s16x8 ld_frag(const ushort_t* p) {
    return __builtin_bit_cast(s16x8, *(const uint4*)p);
}
#define MFMA16(a, b, c) __builtin_amdgcn_mfma_f32_16x16x32_bf16(a, b, c, 0, 0, 0)

// ---------------- 1. landmark means (Q_lm, K_lm), scale+mask folded ----------------
// 256 threads = 4 landmarks x 64 threads.
__global__ __launch_bounds__(256) void lm_kernel(const float* __restrict__ Q, const float* __restrict__ K,
                          const float* __restrict__ M,
                          float* __restrict__ Qlm, float* __restrict__ Klm,
                          uint_t* __restrict__ scal) {
    int g  = blockIdx.x;             // bh*32 + lgrp
    int bh = g >> 5;
    int l  = ((g & 31) << 2) + (threadIdx.x >> 6);
    int b  = bh / NH;
    const float* src = blockIdx.y ? K : Q;
    float* dst = blockIdx.y ? Klm : Qlm;
    int t = threadIdx.x & 63;
    int j0 = t >> 4, d4 = (t & 15) * 4;
    size_t base = ((size_t)bh * SQ + (size_t)l * SEG) * HD;
    int mbase = b * SQ + l * SEG;
    float4 acc = make_float4(0.f, 0.f, 0.f, 0.f);
#pragma unroll
    for (int j = j0; j < SEG; j += 4) {
        float4 v = *(const float4*)(src + base + (size_t)j * HD + d4);
        float m = M[mbase + j];
        acc.x += v.x * m; acc.y += v.y * m; acc.z += v.z * m; acc.w += v.w * m;
    }
    acc.x += __shfl_down(acc.x, 32); acc.y += __shfl_down(acc.y, 32);
    acc.z += __shfl_down(acc.z, 32); acc.w += __shfl_down(acc.w, 32);
    acc.x += __shfl_down(acc.x, 16); acc.y += __shfl_down(acc.y, 16);
    acc.z += __shfl_down(acc.z, 16); acc.w += __shfl_down(acc.w, 16);
    if (t < 16) {
        float s = SCALE / (float)SEG;
        *(float4*)(dst + ((size_t)bh * NL + l) * HD + t * 4) =
            make_float4(acc.x * s, acc.y * s, acc.z * s, acc.w * s);
    }
    if (g == 0 && blockIdx.y == 0 && threadIdx.x < 2) scal[threadIdx.x] = 0u;
}

// ---------------- 2. kernel_2 = softmax(Qlm @ Klm^T) ----------------
__global__ void k2_kernel(const float* __restrict__ Qlm, const float* __restrict__ Klm,
                          float* __restrict__ K2) {
    int bh = blockIdx.x >> 7;
    int c  = threadIdx.x;            // 128 threads = one column each
    int lane = c & 63, wv = c >> 6;
    __shared__ float q[HD];
    __shared__ float red2[4];
    if (c < HD) q[c] = Qlm[(size_t)blockIdx.x * HD + c];
    __syncthreads();
    const float* krow = Klm + ((size_t)bh * NL + c) * HD;
    float s = 0.f;
#pragma unroll
    for (int d = 0; d < HD; d += 4) {
        float4 kv = *(const float4*)(krow + d);
        s += q[d] * kv.x + q[d + 1] * kv.y + q[d + 2] * kv.z + q[d + 3] * kv.w;
    }
    float m = s;
#pragma unroll
    for (int off = 1; off < 64; off <<= 1) m = fmaxf(m, __shfl_xor(m, off));
    if (lane == 0) red2[wv] = m;
    __syncthreads();
    float mx = fmaxf(red2[0], red2[1]);
    float e = __expf(s - mx);
    float se = e;
#pragma unroll
    for (int off = 1; off < 64; off <<= 1) se += __shfl_xor(se, off);
    if (lane == 0) red2[2 + wv] = se;
    __syncthreads();
    float inv = 1.f / (red2[2] + red2[3]);
    K2[(size_t)blockIdx.x * NL + c] = e * inv;
}

// ---------------- 3. global max col-sum -> init_scale (rowsum term == 1) ----------------
__global__ void colmax_kernel(const float* __restrict__ K2, uint_t* __restrict__ scal) {
    int bh = blockIdx.x;
    int tid = threadIdx.x;           // 256
    int c = tid & 127, rh = tid >> 7;
    __shared__ float red[256];
    const float* base = K2 + (size_t)bh * NL * NL;
    float cs = 0.f;
    for (int r = rh * 64; r < rh * 64 + 64; ++r) cs += base[(size_t)r * NL + c];
    red[tid] = cs; __syncthreads();
    if (tid < 128) red[tid] += red[tid + 128];
    __syncthreads();
    for (int st = 64; st > 0; st >>= 1) { if (tid < st) red[tid] = fmaxf(red[tid], red[tid + st]); __syncthreads(); }
    if (tid == 0) atomicMax(&scal[0], __float_as_uint(red[0]));
}

// ---------------- 4. Vm0 = init_scale * K2^T (LDS-tiled transpose) ----------------
__global__ __launch_bounds__(256) void initv_kernel(const float* __restrict__ K2, const uint_t* __restrict__ scal,
                             float* __restrict__ V0) {
    float sc = 1.f / __uint_as_float(scal[0]);   // rowsum factor == 1 exactly
    int bh = blockIdx.z, i0 = blockIdx.x * 64, j0 = blockIdx.y * 64;
    __shared__ float tile[64][65];
    int tid = threadIdx.x;
    const float* src = K2 + (size_t)bh * NL * NL;
#pragma unroll
    for (int rep = 0; rep < 4; ++rep) {
        int r = rep * 16 + (tid >> 4), c4 = (tid & 15) * 4;
        float4 v = *(const float4*)(src + (size_t)(i0 + r) * NL + j0 + c4);
        tile[r][c4 + 0] = v.x; tile[r][c4 + 1] = v.y; tile[r][c4 + 2] = v.z; tile[r][c4 + 3] = v.w;
    }
    __syncthreads();
    float* dst = V0 + (size_t)bh * NL * NL;
#pragma unroll
    for (int rep = 0; rep < 4; ++rep) {
        int r = rep * 16 + (tid >> 4), c4 = (tid & 15) * 4;
        float4 o = make_float4(sc * tile[c4 + 0][r], sc * tile[c4 + 1][r],
                               sc * tile[c4 + 2][r], sc * tile[c4 + 3][r]);
        *(float4*)(dst + (size_t)(j0 + r) * NL + i0 + c4) = o;
    }
}

// ---------------- 5. batched 128x128x128 matmul: C = alpha * A @ (beta*I - B | B) ----------------
// 256 threads, 64x128 block tile, 4x8 per thread -> VALU-bound (32 FMA per 6 LDS ops).
__global__ __launch_bounds__(256) void nw_matmul(const float* __restrict__ A, const float* __restrict__ B,
                                                 float* __restrict__ C, float alpha, float beta, int mode) {
    int bh = blockIdx.y;
    int r0 = blockIdx.x * 64;
    const float* Ab = A + (size_t)bh * NL * NL;
    const float* Bb = B + (size_t)bh * NL * NL;
    float* Cb = C + (size_t)bh * NL * NL;
    __shared__ float Bs[NL][132];    // 67.6 KB, padded row (528 B)
    __shared__ float As[64][132];    // 33.8 KB
    int tid = threadIdx.x;
#pragma unroll
    for (int rep = 0; rep < 16; ++rep) {
        int idx = rep * 256 + tid;       // 4096 float4 = full 128x128 B
        int kr = idx >> 5, c4 = (idx & 31) * 4;
        float4 v = *(const float4*)(Bb + (size_t)kr * NL + c4);
        if (mode) {
            v.x = (kr == c4 + 0 ? beta : 0.f) - v.x;
            v.y = (kr == c4 + 1 ? beta : 0.f) - v.y;
            v.z = (kr == c4 + 2 ? beta : 0.f) - v.z;
            v.w = (kr == c4 + 3 ? beta : 0.f) - v.w;
        }
        *(float4*)&Bs[kr][c4] = v;
    }
#pragma unroll
    for (int rep = 0; rep < 8; ++rep) {
        int idx = rep * 256 + tid;       // 2048 float4 = 64 rows x 128
        int r = idx >> 5, k4 = (idx & 31) * 4;
        float4 v = *(const float4*)(Ab + (size_t)(r0 + r) * NL + k4);
        *(float4*)&As[r][k4] = v;
    }
    __syncthreads();
    int tx = tid & 15, ty = tid >> 4;    // tx 0..15 (8-col groups), ty 0..15 (4-row groups)
    float acc[4][8] = {};
#pragma unroll 4
    for (int k = 0; k < NL; ++k) {
        float4 b0 = *(const float4*)&Bs[k][tx * 8];
        float4 b1 = *(const float4*)&Bs[k][tx * 8 + 4];
        float a0 = As[ty * 4 + 0][k];
        float a1 = As[ty * 4 + 1][k];
        float a2 = As[ty * 4 + 2][k];
        float a3 = As[ty * 4 + 3][k];
        acc[0][0] += a0 * b0.x; acc[0][1] += a0 * b0.y; acc[0][2] += a0 * b0.z; acc[0][3] += a0 * b0.w;
        acc[0][4] += a0 * b1.x; acc[0][5] += a0 * b1.y; acc[0][6] += a0 * b1.z; acc[0][7] += a0 * b1.w;
        acc[1][0] += a1 * b0.x; acc[1][1] += a1 * b0.y; acc[1][2] += a1 * b0.z; acc[1][3] += a1 * b0.w;
        acc[1][4] += a1 * b1.x; acc[1][5] += a1 * b1.y; acc[1][6] += a1 * b1.z; acc[1][7] += a1 * b1.w;
        acc[2][0] += a2 * b0.x; acc[2][1] += a2 * b0.y; acc[2][2] += a2 * b0.z; acc[2][3] += a2 * b0.w;
        acc[2][4] += a2 * b1.x; acc[2][5] += a2 * b1.y; acc[2][6] += a2 * b1.z; acc[2][7] += a2 * b1.w;
        acc[3][0] += a3 * b0.x; acc[3][1] += a3 * b0.y; acc[3][2] += a3 * b0.z; acc[3][3] += a3 * b0.w;
        acc[3][4] += a3 * b1.x; acc[3][5] += a3 * b1.y; acc[3][6] += a3 * b1.z; acc[3][7] += a3 * b1.w;
    }
#pragma unroll
    for (int i = 0; i < 4; ++i) {
        float4 o0 = make_float4(alpha * acc[i][0], alpha * acc[i][1], alpha * acc[i][2], alpha * acc[i][3]);
        float4 o1 = make_float4(alpha * acc[i][4], alpha * acc[i][5], alpha * acc[i][6], alpha * acc[i][7]);
        float* crow = Cb + (size_t)(r0 + ty * 4 + i) * NL + tx * 8;
        *(float4*)crow = o0;
        *(float4*)(crow + 4) = o1;
    }
}

// ---------------- 6a. k3v flash, bf16 MFMA, key-split partials ----------------
// grid (16,48): block = (key-chunk of 256, bh). 8 waves x 16 landmark rows = all 128 rows.
#define KT 64
#define NCK 16
#define KP 72            // padded LDS row stride in ushorts (144 B, 16B-aligned)
__global__ __launch_bounds__(512) void k3v_mfma(const float* __restrict__ K, const float* __restrict__ V,
                                                const float* __restrict__ M, const float* __restrict__ Qlm,
                                                float* __restrict__ Opart, float* __restrict__ Mpart,
                                                float* __restrict__ Lpart) {
    int bh = blockIdx.y, b = bh / NH, ck = blockIdx.x;
    int tid = threadIdx.x;
    int wave = tid >> 6, lane = tid & 63, quad = lane >> 4, l16 = lane & 15;
    __shared__ ushort_t Ksh[KT * KP];          // [key][d] bf16
    __shared__ ushort_t Vsh[HD * KP];          // [d][key^sw] bf16 (transposed, swizzled)
    __shared__ ushort_t Psh[128 * KP];         // per-wave 16-row P regions, swizzled
    __shared__ float msc[KT], mbias[KT];
    int R0 = wave * 16;
    // preload Q A-fragments (constant across key tiles)
    s16x8 aq[2];
#pragma unroll
    for (int ks = 0; ks < 2; ++ks) {
        const float* qp = Qlm + ((size_t)bh * NL + R0 + l16) * HD + ks * 32 + quad * 8;
        float4 q0 = *(const float4*)qp;
        float4 q1 = *(const float4*)(qp + 4);
        aq[ks] = __builtin_bit_cast(s16x8,
            make_uint4(pack2(q0.x, q0.y), pack2(q0.z, q0.w), pack2(q1.x, q1.y), pack2(q1.z, q1.w)));
    }
    float m_run[4], l_run[4];
    f32x4 o[4];
#pragma unroll
    for (int r = 0; r < 4; ++r) { m_run[r] = -1e30f; l_run[r] = 0.f; }
#pragma unroll
    for (int dn = 0; dn < 4; ++dn) o[dn] = (f32x4){0.f, 0.f, 0.f, 0.f};

    const float4* Kg = (const float4*)(K + ((size_t)bh * SQ + ck * 256) * HD);
    const float4* Vg = (const float4*)(V + ((size_t)bh * SQ + ck * 256) * HD);
    const float* Mg = M + b * SQ + ck * 256;

    // prefetch tile 0 (2 float4 per array per thread)
    float4 kreg[2], vreg[2]; float mreg = 0.f;
#pragma unroll
    for (int rep = 0; rep < 2; ++rep) { int idx = rep * 512 + tid; kreg[rep] = Kg[idx]; vreg[rep] = Vg[idx]; }
    if (tid < KT) mreg = Mg[tid];

    int psw = ((wave * 4 + quad) & 7) << 3;           // Psh write-side swizzle (row = wave*16+quad*4+r)
    int asw = ((wave * 4 + (l16 >> 2)) & 7) << 3;     // Psh read-side swizzle (row = wave*16+l16)

    for (int t = 0; t < 4; ++t) {
        __syncthreads();
#pragma unroll
        for (int rep = 0; rep < 2; ++rep) {
            int idx = rep * 512 + tid;          // 1024 float4 = 64 keys x 16
            int key = idx >> 4, d4 = (idx & 15) * 4;
            float4 x = kreg[rep];
            *(uint2*)&Ksh[key * KP + d4] = make_uint2(pack2(x.x, x.y), pack2(x.z, x.w));
            float4 y = vreg[rep];
            int sw = ((d4 >> 2) & 7) << 3;      // same for d4..d4+3
            Vsh[(d4 + 0) * KP + (key ^ sw)] = f2bf(y.x);
            Vsh[(d4 + 1) * KP + (key ^ sw)] = f2bf(y.y);
            Vsh[(d4 + 2) * KP + (key ^ sw)] = f2bf(y.z);
            Vsh[(d4 + 3) * KP + (key ^ sw)] = f2bf(y.w);
        }
        if (tid < KT) {
            msc[tid] = mreg * SCALE;
            mbias[tid] = -NEGBIG * (1.f - mreg);
        }
        __syncthreads();
        if (t < 3) {        // issue next tile's loads; latency hides under compute
#pragma unroll
            for (int rep = 0; rep < 2; ++rep) {
                int idx = rep * 512 + tid;
                kreg[rep] = Kg[(t + 1) * 1024 + idx];
                vreg[rep] = Vg[(t + 1) * 1024 + idx];
            }
            if (tid < KT) mreg = Mg[(t + 1) * KT + tid];
        }
        // ---- QK^T ----
        f32x4 acc[4];
#pragma unroll
        for (int nt = 0; nt < 4; ++nt) acc[nt] = (f32x4){0.f, 0.f, 0.f, 0.f};
#pragma unroll
        for (int nt = 0; nt < 4; ++nt)
#pragma unroll
            for (int ks = 0; ks < 2; ++ks) {
                s16x8 bf = ld_frag(&Ksh[(nt * 16 + l16) * KP + ks * 32 + quad * 8]);
                acc[nt] = MFMA16(aq[ks], bf, acc[nt]);
            }
        float s[4][4];
#pragma unroll
        for (int nt = 0; nt < 4; ++nt) {
            float mm = msc[nt * 16 + l16], bb = mbias[nt * 16 + l16];
#pragma unroll
            for (int r = 0; r < 4; ++r) s[nt][r] = acc[nt][r] * mm + bb;
        }
        float mx[4];
#pragma unroll
        for (int r = 0; r < 4; ++r)
            mx[r] = fmaxf(fmaxf(s[0][r], s[1][r]), fmaxf(s[2][r], s[3][r]));
#pragma unroll
        for (int off = 1; off < 16; off <<= 1)
#pragma unroll
            for (int r = 0; r < 4; ++r) mx[r] = fmaxf(mx[r], __shfl_xor(mx[r], off));
        float al[4];
#pragma unroll
        for (int r = 0; r < 4; ++r) {
            float mn = fmaxf(m_run[r], mx[r]);
            al[r] = __expf(m_run[r] - mn);
            m_run[r] = mn;
        }
        float ps[4] = {0.f, 0.f, 0.f, 0.f};
        int prow = wave * 16;
#pragma unroll
        for (int nt = 0; nt < 4; ++nt)
#pragma unroll
            for (int r = 0; r < 4; ++r) {
                float p = __expf(s[nt][r] - m_run[r]);
                ps[r] += p;
                Psh[(prow + quad * 4 + r) * KP + ((nt * 16 + l16) ^ psw)] = f2bf(p);
            }
#pragma unroll
        for (int off = 1; off < 16; off <<= 1)
#pragma unroll
            for (int r = 0; r < 4; ++r) ps[r] += __shfl_xor(ps[r], off);
#pragma unroll
        for (int r = 0; r < 4; ++r) l_run[r] = l_run[r] * al[r] + ps[r];
#pragma unroll
        for (int dn = 0; dn < 4; ++dn)
#pragma unroll
            for (int r = 0; r < 4; ++r) o[dn][r] *= al[r];
        // ---- PV ----
#pragma unroll
        for (int dn = 0; dn < 4; ++dn)
#pragma unroll
            for (int ks = 0; ks < 2; ++ks) {
                s16x8 af = ld_frag(&Psh[(prow + l16) * KP + ((ks * 32 + quad * 8) ^ asw)]);
                int vrow = dn * 16 + l16;
                int vsw = ((vrow >> 2) & 7) << 3;
                s16x8 bf = ld_frag(&Vsh[vrow * KP + ((ks * 32 + quad * 8) ^ vsw)]);
                o[dn] = MFMA16(af, bf, o[dn]);
            }
    }
    size_t pbase = ((size_t)bh * NCK + ck) * NL;
#pragma unroll
    for (int dn = 0; dn < 4; ++dn)
#pragma unroll
        for (int r = 0; r < 4; ++r) {
            int row = R0 + quad * 4 + r;
            Opart[(pbase + row) * HD + dn * 16 + l16] = o[dn][r];
        }
    if (l16 == 0) {
#pragma unroll
        for (int r = 0; r < 4; ++r) {
            int row = R0 + quad * 4 + r;
            Mpart[pbase + row] = m_run[r];
            Lpart[pbase + row] = l_run[r];
        }
    }
}

// ---------------- 6b. combine key-split partials -> A ----------------
__global__ __launch_bounds__(256) void k3c_kernel(const float* __restrict__ Opart,
                                                  const float* __restrict__ Mpart,
                                                  const float* __restrict__ Lpart,
                                                  float* __restrict__ A) {
    int bh = blockIdx.y;
    int tid = threadIdx.x;
    int r = blockIdx.x * 64 + (tid >> 2);
    int dg = (tid & 3) * 16;
    size_t base = (size_t)bh * NCK * NL;
    float m[NCK], Mx = -1e30f;
#pragma unroll
    for (int ck = 0; ck < NCK; ++ck) { m[ck] = Mpart[base + ck * NL + r]; Mx = fmaxf(Mx, m[ck]); }
    float w[NCK], l = 0.f;
#pragma unroll
    for (int ck = 0; ck < NCK; ++ck) { w[ck] = __expf(m[ck] - Mx); l += w[ck] * Lpart[base + ck * NL + r]; }
    float inv = 1.f / l;
#pragma unroll
    for (int d4 = 0; d4 < 16; d4 += 4) {
        float4 acc = make_float4(0.f, 0.f, 0.f, 0.f);
#pragma unroll
        for (int ck = 0; ck < NCK; ++ck) {
            float4 v = *(const float4*)&Opart[(base + ck * NL + r) * HD + dg + d4];
            acc.x += w[ck] * v.x; acc.y += w[ck] * v.y; acc.z += w[ck] * v.z; acc.w += w[ck] * v.w;
        }
        acc.x *= inv; acc.y *= inv; acc.z *= inv; acc.w *= inv;
        *(float4*)&A[((size_t)bh * NL + r) * HD + dg + d4] = acc;
    }
}

// ---------------- 7. W = Vinv @ A ----------------
__global__ __launch_bounds__(256) void w_kernel(const float* __restrict__ Vinv, const float* __restrict__ A,
                                                float* __restrict__ W) {
    int bh = blockIdx.y;
    int r0 = blockIdx.x * 32;
    __shared__ float Ash[128][64];
    __shared__ float Vl[32][129];
    int tid = threadIdx.x;
    for (int idx = tid; idx < 8192; idx += 256) Ash[idx >> 6][idx & 63] = A[(size_t)bh * 8192 + idx];
    for (int idx = tid; idx < 4096; idx += 256) {
        int r = idx >> 7, k = idx & 127;
        Vl[r][k] = Vinv[(size_t)bh * 16384 + (size_t)(r0 + r) * NL + k];
    }
    __syncthreads();
    int d = tid & 63, rg = tid >> 6;
    float acc[8] = {};
    for (int k = 0; k < NL; ++k) {
        float av = Ash[k][d];
#pragma unroll
        for (int i = 0; i < 8; ++i) acc[i] += Vl[rg * 8 + i][k] * av;
    }
#pragma unroll
    for (int i = 0; i < 8; ++i)
        W[(size_t)bh * 8192 + (size_t)(r0 + rg * 8 + i) * HD + d] = acc[i];
}

// ---------------- 8. X = softmax(Qs @ Klm^T) @ W, bf16 MFMA ----------------
// grid (64,48): block = 64 Q-rows, 4 waves x 16 rows. Wt/Psh XOR-swizzled.
#define QP 72
#define WP 136
__global__ __launch_bounds__(256) void k1x_mfma(const float* __restrict__ Q, const float* __restrict__ M,
                                                const float* __restrict__ Klm, const float* __restrict__ W,
                                                float* __restrict__ out) {
    int bh = blockIdx.y, b = bh / NH, q0 = blockIdx.x * 64;
    int tid = threadIdx.x;
    int wave = tid >> 6, lane = tid & 63, quad = lane >> 4, l16 = lane & 15;
    __shared__ ushort_t Qsh[64 * QP];
    __shared__ ushort_t Bsh[128 * QP];   // Klm tile; reused for P (64*WP=8704 <= 9216)
    __shared__ ushort_t Wt[64 * WP];     // W^T bf16 [d][lm^sw]
    const float4* Qg = (const float4*)(Q + ((size_t)bh * SQ + q0) * HD);
#pragma unroll
    for (int rep = 0; rep < 4; ++rep) {
        int idx = rep * 256 + tid;       // 1024 float4 = 64 rows x 16
        int r = idx >> 4, d4 = (idx & 15) * 4;
        float4 x = Qg[idx];
        float mm = M[b * SQ + q0 + r] * SCALE;
        *(uint2*)&Qsh[r * QP + d4] = make_uint2(pack2(x.x * mm, x.y * mm), pack2(x.z * mm, x.w * mm));
    }
    const float4* Kg = (const float4*)(Klm + (size_t)bh * NL * HD);
#pragma unroll
    for (int rep = 0; rep < 8; ++rep) {
        int idx = rep * 256 + tid;       // 2048 float4 = 128 rows x 16
        int r = idx >> 4, d4 = (idx & 15) * 4;
        float4 x = Kg[idx];
        *(uint2*)&Bsh[r * QP + d4] = make_uint2(pack2(x.x, x.y), pack2(x.z, x.w));
    }
    const float4* Wg = (const float4*)(W + (size_t)bh * NL * HD);
#pragma unroll
    for (int rep = 0; rep < 8; ++rep) {
        int idx = rep * 256 + tid;       // 2048 float4 = 128 lm x 16
        int lm = idx >> 4, d4 = (idx & 15) * 4;
        float4 x = Wg[idx];
        int sw = ((d4 >> 2) & 7) << 3;   // same for d4..d4+3
        Wt[(d4 + 0) * WP + (lm ^ sw)] = f2bf(x.x);
        Wt[(d4 + 1) * WP + (lm ^ sw)] = f2bf(x.y);
        Wt[(d4 + 2) * WP + (lm ^ sw)] = f2bf(x.z);
        Wt[(d4 + 3) * WP + (lm ^ sw)] = f2bf(x.w);
    }
    __syncthreads();
    int R = wave * 16;
    s16x8 aq[2];
#pragma unroll
    for (int ks = 0; ks < 2; ++ks) aq[ks] = ld_frag(&Qsh[(R + l16) * QP + ks * 32 + quad * 8]);
    f32x4 acc[8];
#pragma unroll
    for (int nt = 0; nt < 8; ++nt) acc[nt] = (f32x4){0.f, 0.f, 0.f, 0.f};
#pragma unroll
    for (int nt = 0; nt < 8; ++nt)
#pragma unroll
        for (int ks = 0; ks < 2; ++ks) {
            s16x8 bf = ld_frag(&Bsh[(nt * 16 + l16) * QP + ks * 32 + quad * 8]);
            acc[nt] = MFMA16(aq[ks], bf, acc[nt]);
        }
    float mx[4];
#pragma unroll
    for (int r = 0; r < 4; ++r) {
        mx[r] = acc[0][r];
#pragma unroll
        for (int nt = 1; nt < 8; ++nt) mx[r] = fmaxf(mx[r], acc[nt][r]);
    }
#pragma unroll
    for (int off = 1; off < 16; off <<= 1)
#pragma unroll
        for (int r = 0; r < 4; ++r) mx[r] = fmaxf(mx[r], __shfl_xor(mx[r], off));
    float ps[4] = {0.f, 0.f, 0.f, 0.f};
#pragma unroll
    for (int nt = 0; nt < 8; ++nt)
#pragma unroll
        for (int r = 0; r < 4; ++r) {
            float p = __expf(acc[nt][r] - mx[r]);
            acc[nt][r] = p;
            ps[r] += p;
        }
#pragma unroll
    for (int off = 1; off < 16; off <<= 1)
#pragma unroll
        for (int r = 0; r < 4; ++r) ps[r] += __shfl_xor(ps[r], off);
    float inv[4];
#pragma unroll
    for (int r = 0; r < 4; ++r) inv[r] = 1.f / ps[r];
    __syncthreads();                     // all waves done reading Bsh (Klm)
    ushort_t* Psh = Bsh;
    int psw = ((wave * 4 + quad) & 7) << 3;        // row = R+quad*4+r
    int asw = ((wave * 4 + (l16 >> 2)) & 7) << 3;  // row = R+l16
#pragma unroll
    for (int nt = 0; nt < 8; ++nt)
#pragma unroll
        for (int r = 0; r < 4; ++r)
            Psh[(R + quad * 4 + r) * WP + ((nt * 16 + l16) ^ psw)] = f2bf(acc[nt][r] * inv[r]);
    // PV: each wave reads only its own P rows -> no extra barrier (lgkmcnt orders within wave)
    f32x4 o[4];
#pragma unroll
    for (int dn = 0; dn < 4; ++dn) o[dn] = (f32x4){0.f, 0.f, 0.f, 0.f};
#pragma unroll
    for (int dn = 0; dn < 4; ++dn)
#pragma unroll
        for (int ks = 0; ks < 4; ++ks) {
            s16x8 af = ld_frag(&Psh[(R + l16) * WP + ((ks * 32 + quad * 8) ^ asw)]);
            int vrow = dn * 16 + l16;
            int wsw = ((vrow >> 2) & 7) << 3;
            s16x8 bf = ld_frag(&Wt[vrow * WP + ((ks * 32 + quad * 8) ^ wsw)]);
            o[dn] = MFMA16(af, bf, o[dn]);
        }
    float* op = out + ((size_t)bh * SQ + q0) * HD;
#pragma unroll
    for (int dn = 0; dn < 4; ++dn)
#pragma unroll
        for (int r = 0; r < 4; ++r)
            op[(R + quad * 4 + r) * HD + dn * 16 + l16] = o[dn][r];
}

extern "C" void kernel_launch(void* const* d_in, const int* in_sizes, int n_in,
                              void* d_out, int out_size, void* d_ws, size_t ws_size,
                              hipStream_t stream) {
    const float* Q = (const float*)d_in[0];
    const float* K = (const float*)d_in[1];
    const float* V = (const float*)d_in[2];
    const float* M = (const float*)d_in[3];
    float* out = (float*)d_out;

    float* ws  = (float*)d_ws;
    float* Qlm = ws;                 // 48*128*64
    float* Klm = Qlm + 393216;
    float* K2  = Klm + 393216;       // 48*128*128
    float* Vm0 = K2  + 786432;
    float* Vm1 = Vm0 + 786432;
    float* KV  = Vm1 + 786432;
    float* T1  = KV  + 786432;
    float* T2  = T1  + 786432;
    float* Ab  = T2  + 786432;       // 48*128*64
    float* Wb  = Ab  + 393216;
    uint_t* scal  = (uint_t*)(Wb + 393216);
    float* Mpart = Wb + 393216 + 16;     // 48*16*128
    float* Lpart = Mpart + 98304;
    float* Opart = Lpart + 98304;        // 48*16*128*64 = 6291456 floats

    lm_kernel<<<dim3(1536, 2), 256, 0, stream>>>(Q, K, M, Qlm, Klm, scal);
    k2_kernel<<<6144, 128, 0, stream>>>(Qlm, Klm, K2);
    colmax_kernel<<<48, 256, 0, stream>>>(K2, scal);
    initv_kernel<<<dim3(2, 2, 48), 256, 0, stream>>>(K2, scal, Vm0);

    float* Vc = Vm0; float* Vn = Vm1;
    for (int it = 0; it < 6; ++it) {
        nw_matmul<<<dim3(2, 48), 256, 0, stream>>>(K2, Vc, KV, 1.f, 0.f, 0);   // KV = Km@Vm
        nw_matmul<<<dim3(2, 48), 256, 0, stream>>>(KV, KV, T1, 1.f, 7.f, 1);   // T1 = KV@(7I-KV)
        nw_matmul<<<dim3(2, 48), 256, 0, stream>>>(KV, T1, T2, 1.f, 15.f, 1);  // T2 = KV@(15I-T1)
        nw_matmul<<<dim3(2, 48), 256, 0, stream>>>(Vc, T2, Vn, 0.25f, 13.f, 1);// Vn = .25*Vm@(13I-T2)
        float* t = Vc; Vc = Vn; Vn = t;
    }
    // after 6 iterations Vc == Vm0

    k3v_mfma<<<dim3(NCK, 48), 512, 0, stream>>>(K, V, M, Qlm, Opart, Mpart, Lpart);
    k3c_kernel<<<dim3(2, 48), 256, 0, stream>>>(Opart, Mpart, Lpart, Ab);
    w_kernel<<<dim3(4, 48), 256, 0, stream>>>(Vm0, Ab, Wb);
    k1x_mfma<<<dim3(64, 48), 256, 0, stream>>>(Q, M, Klm, Wb, out);
}

// Round 6
// 436.774 us; speedup vs baseline: 1.3708x; 1.3708x over previous
//
#include <hip/hip_runtime.h>

// NystromAttention on MI355X. fp32 I/O, bf16 MFMA for the two big attention
// matmuls (k3v flash + k1x). Newton chain: iterations 0-4 via split-bf16 MFMA
// (a=ah+al; ab ~= ah*bh+ah*bl+al*bh, fp32 accum), final iteration 5 in pure
// fp32 VALU (proven round-4 kernel) so Newton self-correction restores
// near-fp32 quality. grid.sync banned (~30us/sync); 24 small launches instead.

typedef unsigned int uint_t;
typedef unsigned short ushort_t;
typedef short s16x8 __attribute__((ext_vector_type(8)));
typedef float f32x4 __attribute__((ext_vector_type(4)));

#define NB 4
#define NH 12
#define BH 48
#define SQ 4096
#define HD 64
#define NL 128
#define SEG 32
#define SCALE 0.35355339059327379f
#define NEGBIG 1.0e9f

__device__ __forceinline__ ushort_t f2bf(float f) {
    uint_t u = __float_as_uint(f);
    u += 0x7FFFu + ((u >> 16) & 1u);   // RNE
    return (ushort_t)(u >> 16);
}
__device__ __forceinline__ float bf2f(ushort_t h) {
    return __uint_as_float((uint_t)h << 16);
}
__device__ __forceinline__ uint_t pack2(float a, float b) {
    return (uint_t)f2bf(a) | ((uint_t)f2bf(b) << 16);
}
__device__ __forceinline__ s16x8 ld_frag(const ushort_t* p) {
    return __builtin_bit_cast(s16x8, *(const uint4*)p);
}
#define MFMA16(a, b, c) __builtin_amdgcn_mfma_f32_16x16x32_bf16(a, b, c, 0, 0, 0)

// ---------------- 1. landmark means (Q_lm, K_lm), scale+mask folded ----------------
__global__ __launch_bounds__(256) void lm_kernel(const float* __restrict__ Q, const float* __restrict__ K,
                          const float* __restrict__ M,
                          float* __restrict__ Qlm, float* __restrict__ Klm,
                          uint_t* __restrict__ scal) {
    int g  = blockIdx.x;             // bh*32 + lgrp
    int bh = g >> 5;
    int l  = ((g & 31) << 2) + (threadIdx.x >> 6);
    int b  = bh / NH;
    const float* src = blockIdx.y ? K : Q;
    float* dst = blockIdx.y ? Klm : Qlm;
    int t = threadIdx.x & 63;
    int j0 = t >> 4, d4 = (t & 15) * 4;
    size_t base = ((size_t)bh * SQ + (size_t)l * SEG) * HD;
    int mbase = b * SQ + l * SEG;
    float4 acc = make_float4(0.f, 0.f, 0.f, 0.f);
#pragma unroll
    for (int j = j0; j < SEG; j += 4) {
        float4 v = *(const float4*)(src + base + (size_t)j * HD + d4);
        float m = M[mbase + j];
        acc.x += v.x * m; acc.y += v.y * m; acc.z += v.z * m; acc.w += v.w * m;
    }
    acc.x += __shfl_down(acc.x, 32); acc.y += __shfl_down(acc.y, 32);
    acc.z += __shfl_down(acc.z, 32); acc.w += __shfl_down(acc.w, 32);
    acc.x += __shfl_down(acc.x, 16); acc.y += __shfl_down(acc.y, 16);
    acc.z += __shfl_down(acc.z, 16); acc.w += __shfl_down(acc.w, 16);
    if (t < 16) {
        float s = SCALE / (float)SEG;
        *(float4*)(dst + ((size_t)bh * NL + l) * HD + t * 4) =
            make_float4(acc.x * s, acc.y * s, acc.z * s, acc.w * s);
    }
    if (g == 0 && blockIdx.y == 0 && threadIdx.x < 2) scal[threadIdx.x] = 0u;
}

// ---------------- 2. kernel_2 = softmax(Qlm @ Klm^T) ----------------
__global__ void k2_kernel(const float* __restrict__ Qlm, const float* __restrict__ Klm,
                          float* __restrict__ K2) {
    int bh = blockIdx.x >> 7;
    int c  = threadIdx.x;            // 128 threads = one column each
    int lane = c & 63, wv = c >> 6;
    __shared__ float q[HD];
    __shared__ float red2[4];
    if (c < HD) q[c] = Qlm[(size_t)blockIdx.x * HD + c];
    __syncthreads();
    const float* krow = Klm + ((size_t)bh * NL + c) * HD;
    float s = 0.f;
#pragma unroll
    for (int d = 0; d < HD; d += 4) {
        float4 kv = *(const float4*)(krow + d);
        s += q[d] * kv.x + q[d + 1] * kv.y + q[d + 2] * kv.z + q[d + 3] * kv.w;
    }
    float m = s;
#pragma unroll
    for (int off = 1; off < 64; off <<= 1) m = fmaxf(m, __shfl_xor(m, off));
    if (lane == 0) red2[wv] = m;
    __syncthreads();
    float mx = fmaxf(red2[0], red2[1]);
    float e = __expf(s - mx);
    float se = e;
#pragma unroll
    for (int off = 1; off < 64; off <<= 1) se += __shfl_xor(se, off);
    if (lane == 0) red2[2 + wv] = se;
    __syncthreads();
    float inv = 1.f / (red2[2] + red2[3]);
    K2[(size_t)blockIdx.x * NL + c] = e * inv;
}

// ---------------- 3. global max col-sum -> init_scale (rowsum term == 1) ----------------
__global__ void colmax_kernel(const float* __restrict__ K2, uint_t* __restrict__ scal) {
    int bh = blockIdx.x;
    int tid = threadIdx.x;           // 256
    int c = tid & 127, rh = tid >> 7;
    __shared__ float red[256];
    const float* base = K2 + (size_t)bh * NL * NL;
    float cs = 0.f;
    for (int r = rh * 64; r < rh * 64 + 64; ++r) cs += base[(size_t)r * NL + c];
    red[tid] = cs; __syncthreads();
    if (tid < 128) red[tid] += red[tid + 128];
    __syncthreads();
    for (int st = 64; st > 0; st >>= 1) { if (tid < st) red[tid] = fmaxf(red[tid], red[tid + st]); __syncthreads(); }
    if (tid == 0) atomicMax(&scal[0], __float_as_uint(red[0]));
}

// ---------------- 4. Vm0 = init_scale * K2^T (LDS-tiled transpose) ----------------
__global__ __launch_bounds__(256) void initv_kernel(const float* __restrict__ K2, const uint_t* __restrict__ scal,
                             float* __restrict__ V0) {
    float sc = 1.f / __uint_as_float(scal[0]);   // rowsum factor == 1 exactly
    int bh = blockIdx.z, i0 = blockIdx.x * 64, j0 = blockIdx.y * 64;
    __shared__ float tile[64][65];
    int tid = threadIdx.x;
    const float* src = K2 + (size_t)bh * NL * NL;
#pragma unroll
    for (int rep = 0; rep < 4; ++rep) {
        int r = rep * 16 + (tid >> 4), c4 = (tid & 15) * 4;
        float4 v = *(const float4*)(src + (size_t)(i0 + r) * NL + j0 + c4);
        tile[r][c4 + 0] = v.x; tile[r][c4 + 1] = v.y; tile[r][c4 + 2] = v.z; tile[r][c4 + 3] = v.w;
    }
    __syncthreads();
    float* dst = V0 + (size_t)bh * NL * NL;
#pragma unroll
    for (int rep = 0; rep < 4; ++rep) {
        int r = rep * 16 + (tid >> 4), c4 = (tid & 15) * 4;
        float4 o = make_float4(sc * tile[c4 + 0][r], sc * tile[c4 + 1][r],
                               sc * tile[c4 + 2][r], sc * tile[c4 + 3][r]);
        *(float4*)(dst + (size_t)(j0 + r) * NL + i0 + c4) = o;
    }
}

// ---------------- 5a. Newton matmul via split-bf16 MFMA (iterations 0-4) ----------------
// C = alpha * A @ (beta*I - B | B). grid (2,48) x 512 thr. A-half + B^T staged
// hi/lo bf16 in LDS (B^T with k3v-style XOR swizzle). Wave = 32x32 output.
#define NWP 136          // LDS row stride in ushorts (272 B = 17x16B)
__global__ __launch_bounds__(512) void nw_mfma(const float* __restrict__ A, const float* __restrict__ B,
                                               float* __restrict__ C, float alpha, float beta, int mode) {
    int bh = blockIdx.y;
    int r0 = blockIdx.x * 64;
    const float* Ab = A + (size_t)bh * NL * NL;
    const float* Bb = B + (size_t)bh * NL * NL;
    float* Cb = C + (size_t)bh * NL * NL;
    __shared__ ushort_t Ah[64 * NWP], Al[64 * NWP];      // A rows, hi/lo
    __shared__ ushort_t Bh[128 * NWP], Bl[128 * NWP];    // B~^T [col][k^sw], hi/lo
    int tid = threadIdx.x;
    // stage A rows r0..r0+63 (2048 float4)
#pragma unroll
    for (int rep = 0; rep < 4; ++rep) {
        int idx = rep * 512 + tid;
        int r = idx >> 5, c4 = (idx & 31) * 4;
        float4 v = *(const float4*)(Ab + (size_t)(r0 + r) * NL + c4);
        ushort_t h0 = f2bf(v.x), h1 = f2bf(v.y), h2 = f2bf(v.z), h3 = f2bf(v.w);
        ushort_t l0 = f2bf(v.x - bf2f(h0)), l1 = f2bf(v.y - bf2f(h1));
        ushort_t l2 = f2bf(v.z - bf2f(h2)), l3 = f2bf(v.w - bf2f(h3));
        *(uint2*)&Ah[r * NWP + c4] = make_uint2((uint_t)h0 | ((uint_t)h1 << 16), (uint_t)h2 | ((uint_t)h3 << 16));
        *(uint2*)&Al[r * NWP + c4] = make_uint2((uint_t)l0 | ((uint_t)l1 << 16), (uint_t)l2 | ((uint_t)l3 << 16));
    }
    // stage B~^T: 2048 tasks = 64 k-pairs x 32 col-quads; pair-packed b32 stores
#pragma unroll
    for (int rep = 0; rep < 4; ++rep) {
        int idx = rep * 512 + tid;
        int kp = idx >> 5, c4 = (idx & 31) * 4;
        int k0 = kp * 2;
        const float* bp = Bb + (size_t)k0 * NL + c4;
        float4 v0 = *(const float4*)bp;
        float4 v1 = *(const float4*)(bp + NL);
        if (mode) {
            v0.x = (k0 == c4 + 0 ? beta : 0.f) - v0.x;
            v0.y = (k0 == c4 + 1 ? beta : 0.f) - v0.y;
            v0.z = (k0 == c4 + 2 ? beta : 0.f) - v0.z;
            v0.w = (k0 == c4 + 3 ? beta : 0.f) - v0.w;
            v1.x = (k0 + 1 == c4 + 0 ? beta : 0.f) - v1.x;
            v1.y = (k0 + 1 == c4 + 1 ? beta : 0.f) - v1.y;
            v1.z = (k0 + 1 == c4 + 2 ? beta : 0.f) - v1.z;
            v1.w = (k0 + 1 == c4 + 3 ? beta : 0.f) - v1.w;
        }
#define BPUT(cc, x0, x1) { int c_ = (cc); int sw_ = ((c_ >> 2) & 7) << 3; int ko_ = k0 ^ sw_; \
        ushort_t hh0 = f2bf(x0), hh1 = f2bf(x1); \
        ushort_t ll0 = f2bf((x0) - bf2f(hh0)), ll1 = f2bf((x1) - bf2f(hh1)); \
        *(uint_t*)&Bh[c_ * NWP + ko_] = (uint_t)hh0 | ((uint_t)hh1 << 16); \
        *(uint_t*)&Bl[c_ * NWP + ko_] = (uint_t)ll0 | ((uint_t)ll1 << 16); }
        BPUT(c4 + 0, v0.x, v1.x)
        BPUT(c4 + 1, v0.y, v1.y)
        BPUT(c4 + 2, v0.z, v1.z)
        BPUT(c4 + 3, v0.w, v1.w)
#undef BPUT
    }
    __syncthreads();
    int wave = tid >> 6, lane = tid & 63, quad = lane >> 4, l16 = lane & 15;
    int rg = (wave & 1) * 32;        // row-group within the 64-row half
    int cg = (wave >> 1) * 32;       // col-group (4 groups of 32)
    f32x4 acc[2][2];
#pragma unroll
    for (int rf = 0; rf < 2; ++rf)
#pragma unroll
        for (int cf = 0; cf < 2; ++cf) acc[rf][cf] = (f32x4){0.f, 0.f, 0.f, 0.f};
#pragma unroll
    for (int ks = 0; ks < 4; ++ks) {
        int kof = ks * 32 + quad * 8;
        s16x8 ah0 = ld_frag(&Ah[(rg + l16) * NWP + kof]);
        s16x8 al0 = ld_frag(&Al[(rg + l16) * NWP + kof]);
        s16x8 ah1 = ld_frag(&Ah[(rg + 16 + l16) * NWP + kof]);
        s16x8 al1 = ld_frag(&Al[(rg + 16 + l16) * NWP + kof]);
#pragma unroll
        for (int cf = 0; cf < 2; ++cf) {
            int c = cg + cf * 16 + l16;
            int sw = ((c >> 2) & 7) << 3;
            s16x8 bh = ld_frag(&Bh[c * NWP + (kof ^ sw)]);
            s16x8 bl = ld_frag(&Bl[c * NWP + (kof ^ sw)]);
            acc[0][cf] = MFMA16(ah0, bh, acc[0][cf]);
            acc[0][cf] = MFMA16(ah0, bl, acc[0][cf]);
            acc[0][cf] = MFMA16(al0, bh, acc[0][cf]);
            acc[1][cf] = MFMA16(ah1, bh, acc[1][cf]);
            acc[1][cf] = MFMA16(ah1, bl, acc[1][cf]);
            acc[1][cf] = MFMA16(al1, bh, acc[1][cf]);
        }
    }
#pragma unroll
    for (int rf = 0; rf < 2; ++rf)
#pragma unroll
        for (int cf = 0; cf < 2; ++cf)
#pragma unroll
            for (int i = 0; i < 4; ++i)
                Cb[(size_t)(r0 + rg + rf * 16 + quad * 4 + i) * NL + cg + cf * 16 + l16] =
                    alpha * acc[rf][cf][i];
}

// ---------------- 5b. fp32 Newton matmul (final iteration) — proven round-4 kernel ----------------
__global__ __launch_bounds__(512) void nw_matmul(const float* __restrict__ A, const float* __restrict__ B,
                                                 float* __restrict__ C, float alpha, float beta, int mode) {
    int bh = blockIdx.y;
    int r0 = blockIdx.x * 32;
    const float* Ab = A + (size_t)bh * NL * NL;
    const float* Bb = B + (size_t)bh * NL * NL;
    float* Cb = C + (size_t)bh * NL * NL;
    __shared__ float Bs[NL][NL];     // 64 KB
    __shared__ float As[32][132];    // row-major, 528B row stride (16B aligned)
    int tid = threadIdx.x;
    int tx = tid & 31, ty = tid >> 5;   // ty 0..15
#pragma unroll
    for (int rep = 0; rep < 8; ++rep) {
        int idx = rep * 512 + tid;       // 4096 float4 = full 128x128 B
        int kr = idx >> 5, c4 = (idx & 31) * 4;
        float4 v = *(const float4*)(Bb + (size_t)kr * NL + c4);
        if (mode) {
            v.x = (kr == c4 + 0 ? beta : 0.f) - v.x;
            v.y = (kr == c4 + 1 ? beta : 0.f) - v.y;
            v.z = (kr == c4 + 2 ? beta : 0.f) - v.z;
            v.w = (kr == c4 + 3 ? beta : 0.f) - v.w;
        }
        *(float4*)&Bs[kr][c4] = v;
    }
#pragma unroll
    for (int rep = 0; rep < 2; ++rep) {
        int idx = rep * 512 + tid;       // 1024 float4 = 32 rows x 128
        int r = idx >> 5, k4 = (idx & 31) * 4;
        float4 v = *(const float4*)(Ab + (size_t)(r0 + r) * NL + k4);
        *(float4*)&As[r][k4] = v;
    }
    __syncthreads();
    float acc[2][4] = {};
#pragma unroll 4
    for (int k = 0; k < NL; ++k) {
        float a0 = As[ty * 2 + 0][k];
        float a1 = As[ty * 2 + 1][k];
        float4 bb = *(const float4*)&Bs[k][tx * 4];
        acc[0][0] += a0 * bb.x; acc[0][1] += a0 * bb.y; acc[0][2] += a0 * bb.z; acc[0][3] += a0 * bb.w;
        acc[1][0] += a1 * bb.x; acc[1][1] += a1 * bb.y; acc[1][2] += a1 * bb.z; acc[1][3] += a1 * bb.w;
    }
#pragma unroll
    for (int i = 0; i < 2; ++i) {
        float4 o = make_float4(alpha * acc[i][0], alpha * acc[i][1],
                               alpha * acc[i][2], alpha * acc[i][3]);
        *(float4*)(Cb + (size_t)(r0 + ty * 2 + i) * NL + tx * 4) = o;
    }
}

// ---------------- 6a. k3v flash, bf16 MFMA, key-split partials ----------------
// grid (16,48): block = (key-chunk of 256, bh). 8 waves x 16 landmark rows = all 128 rows.
#define KT 64
#define NCK 16
#define KP 72            // padded LDS row stride in ushorts (144 B, 16B-aligned)
__global__ __launch_bounds__(512) void k3v_mfma(const float* __restrict__ K, const float* __restrict__ V,
                                                const float* __restrict__ M, const float* __restrict__ Qlm,
                                                float* __restrict__ Opart, float* __restrict__ Mpart,
                                                float* __restrict__ Lpart) {
    int bh = blockIdx.y, b = bh / NH, ck = blockIdx.x;
    int tid = threadIdx.x;
    int wave = tid >> 6, lane = tid & 63, quad = lane >> 4, l16 = lane & 15;
    __shared__ ushort_t Ksh[KT * KP];          // [key][d] bf16
    __shared__ ushort_t Vsh[HD * KP];          // [d][key^sw] bf16 (transposed, swizzled)
    __shared__ ushort_t Psh[128 * KP];         // per-wave 16-row P regions, swizzled
    __shared__ float msc[KT], mbias[KT];
    int R0 = wave * 16;
    // preload Q A-fragments (constant across key tiles)
    s16x8 aq[2];
#pragma unroll
    for (int ks = 0; ks < 2; ++ks) {
        const float* qp = Qlm + ((size_t)bh * NL + R0 + l16) * HD + ks * 32 + quad * 8;
        float4 q0 = *(const float4*)qp;
        float4 q1 = *(const float4*)(qp + 4);
        aq[ks] = __builtin_bit_cast(s16x8,
            make_uint4(pack2(q0.x, q0.y), pack2(q0.z, q0.w), pack2(q1.x, q1.y), pack2(q1.z, q1.w)));
    }
    float m_run[4], l_run[4];
    f32x4 o[4];
#pragma unroll
    for (int r = 0; r < 4; ++r) { m_run[r] = -1e30f; l_run[r] = 0.f; }
#pragma unroll
    for (int dn = 0; dn < 4; ++dn) o[dn] = (f32x4){0.f, 0.f, 0.f, 0.f};

    const float4* Kg = (const float4*)(K + ((size_t)bh * SQ + ck * 256) * HD);
    const float4* Vg = (const float4*)(V + ((size_t)bh * SQ + ck * 256) * HD);
    const float* Mg = M + b * SQ + ck * 256;

    // prefetch tile 0 (2 float4 per array per thread)
    float4 kreg[2], vreg[2]; float mreg = 0.f;
#pragma unroll
    for (int rep = 0; rep < 2; ++rep) { int idx = rep * 512 + tid; kreg[rep] = Kg[idx]; vreg[rep] = Vg[idx]; }
    if (tid < KT) mreg = Mg[tid];

    int psw = ((wave * 4 + quad) & 7) << 3;           // Psh write-side swizzle (row = wave*16+quad*4+r)
    int asw = ((wave * 4 + (l16 >> 2)) & 7) << 3;     // Psh read-side swizzle (row = wave*16+l16)

    for (int t = 0; t < 4; ++t) {
        __syncthreads();
#pragma unroll
        for (int rep = 0; rep < 2; ++rep) {
            int idx = rep * 512 + tid;          // 1024 float4 = 64 keys x 16
            int key = idx >> 4, d4 = (idx & 15) * 4;
            float4 x = kreg[rep];
            *(uint2*)&Ksh[key * KP + d4] = make_uint2(pack2(x.x, x.y), pack2(x.z, x.w));
            float4 y = vreg[rep];
            int sw = ((d4 >> 2) & 7) << 3;      // same for d4..d4+3
            Vsh[(d4 + 0) * KP + (key ^ sw)] = f2bf(y.x);
            Vsh[(d4 + 1) * KP + (key ^ sw)] = f2bf(y.y);
            Vsh[(d4 + 2) * KP + (key ^ sw)] = f2bf(y.z);
            Vsh[(d4 + 3) * KP + (key ^ sw)] = f2bf(y.w);
        }
        if (tid < KT) {
            msc[tid] = mreg * SCALE;
            mbias[tid] = -NEGBIG * (1.f - mreg);
        }
        __syncthreads();
        if (t < 3) {        // issue next tile's loads; latency hides under compute
#pragma unroll
            for (int rep = 0; rep < 2; ++rep) {
                int idx = rep * 512 + tid;
                kreg[rep] = Kg[(t + 1) * 1024 + idx];
                vreg[rep] = Vg[(t + 1) * 1024 + idx];
            }
            if (tid < KT) mreg = Mg[(t + 1) * KT + tid];
        }
        // ---- QK^T ----
        f32x4 acc[4];
#pragma unroll
        for (int nt = 0; nt < 4; ++nt) acc[nt] = (f32x4){0.f, 0.f, 0.f, 0.f};
#pragma unroll
        for (int nt = 0; nt < 4; ++nt)
#pragma unroll
            for (int ks = 0; ks < 2; ++ks) {
                s16x8 bf = ld_frag(&Ksh[(nt * 16 + l16) * KP + ks * 32 + quad * 8]);
                acc[nt] = MFMA16(aq[ks], bf, acc[nt]);
            }
        float s[4][4];
#pragma unroll
        for (int nt = 0; nt < 4; ++nt) {
            float mm = msc[nt * 16 + l16], bb = mbias[nt * 16 + l16];
#pragma unroll
            for (int r = 0; r < 4; ++r) s[nt][r] = acc[nt][r] * mm + bb;
        }
        float mx[4];
#pragma unroll
        for (int r = 0; r < 4; ++r)
            mx[r] = fmaxf(fmaxf(s[0][r], s[1][r]), fmaxf(s[2][r], s[3][r]));
#pragma unroll
        for (int off = 1; off < 16; off <<= 1)
#pragma unroll
            for (int r = 0; r < 4; ++r) mx[r] = fmaxf(mx[r], __shfl_xor(mx[r], off));
        float al[4];
#pragma unroll
        for (int r = 0; r < 4; ++r) {
            float mn = fmaxf(m_run[r], mx[r]);
            al[r] = __expf(m_run[r] - mn);
            m_run[r] = mn;
        }
        float ps[4] = {0.f, 0.f, 0.f, 0.f};
        int prow = wave * 16;
#pragma unroll
        for (int nt = 0; nt < 4; ++nt)
#pragma unroll
            for (int r = 0; r < 4; ++r) {
                float p = __expf(s[nt][r] - m_run[r]);
                ps[r] += p;
                Psh[(prow + quad * 4 + r) * KP + ((nt * 16 + l16) ^ psw)] = f2bf(p);
            }
#pragma unroll
        for (int off = 1; off < 16; off <<= 1)
#pragma unroll
            for (int r = 0; r < 4; ++r) ps[r] += __shfl_xor(ps[r], off);
#pragma unroll
        for (int r = 0; r < 4; ++r) l_run[r] = l_run[r] * al[r] + ps[r];
#pragma unroll
        for (int dn = 0; dn < 4; ++dn)
#pragma unroll
            for (int r = 0; r < 4; ++r) o[dn][r] *= al[r];
        // ---- PV ----
#pragma unroll
        for (int dn = 0; dn < 4; ++dn)
#pragma unroll
            for (int ks = 0; ks < 2; ++ks) {
                s16x8 af = ld_frag(&Psh[(prow + l16) * KP + ((ks * 32 + quad * 8) ^ asw)]);
                int vrow = dn * 16 + l16;
                int vsw = ((vrow >> 2) & 7) << 3;
                s16x8 bf = ld_frag(&Vsh[vrow * KP + ((ks * 32 + quad * 8) ^ vsw)]);
                o[dn] = MFMA16(af, bf, o[dn]);
            }
    }
    size_t pbase = ((size_t)bh * NCK + ck) * NL;
#pragma unroll
    for (int dn = 0; dn < 4; ++dn)
#pragma unroll
        for (int r = 0; r < 4; ++r) {
            int row = R0 + quad * 4 + r;
            Opart[(pbase + row) * HD + dn * 16 + l16] = o[dn][r];
        }
    if (l16 == 0) {
#pragma unroll
        for (int r = 0; r < 4; ++r) {
            int row = R0 + quad * 4 + r;
            Mpart[pbase + row] = m_run[r];
            Lpart[pbase + row] = l_run[r];
        }
    }
}

// ---------------- 6b. combine key-split partials -> A ----------------
__global__ __launch_bounds__(256) void k3c_kernel(const float* __restrict__ Opart,
                                                  const float* __restrict__ Mpart,
                                                  const float* __restrict__ Lpart,
                                                  float* __restrict__ A) {
    int bh = blockIdx.y;
    int tid = threadIdx.x;
    int r = blockIdx.x * 64 + (tid >> 2);
    int dg = (tid & 3) * 16;
    size_t base = (size_t)bh * NCK * NL;
    float m[NCK], Mx = -1e30f;
#pragma unroll
    for (int ck = 0; ck < NCK; ++ck) { m[ck] = Mpart[base + ck * NL + r]; Mx = fmaxf(Mx, m[ck]); }
    float w[NCK], l = 0.f;
#pragma unroll
    for (int ck = 0; ck < NCK; ++ck) { w[ck] = __expf(m[ck] - Mx); l += w[ck] * Lpart[base + ck * NL + r]; }
    float inv = 1.f / l;
#pragma unroll
    for (int d4 = 0; d4 < 16; d4 += 4) {
        float4 acc = make_float4(0.f, 0.f, 0.f, 0.f);
#pragma unroll
        for (int ck = 0; ck < NCK; ++ck) {
            float4 v = *(const float4*)&Opart[(base + ck * NL + r) * HD + dg + d4];
            acc.x += w[ck] * v.x; acc.y += w[ck] * v.y; acc.z += w[ck] * v.z; acc.w += w[ck] * v.w;
        }
        acc.x *= inv; acc.y *= inv; acc.z *= inv; acc.w *= inv;
        *(float4*)&A[((size_t)bh * NL + r) * HD + dg + d4] = acc;
    }
}

// ---------------- 7. W = Vinv @ A ----------------
__global__ __launch_bounds__(256) void w_kernel(const float* __restrict__ Vinv, const float* __restrict__ A,
                                                float* __restrict__ W) {
    int bh = blockIdx.y;
    int r0 = blockIdx.x * 32;
    __shared__ float Ash[128][64];
    __shared__ float Vl[32][129];
    int tid = threadIdx.x;
    for (int idx = tid; idx < 8192; idx += 256) Ash[idx >> 6][idx & 63] = A[(size_t)bh * 8192 + idx];
    for (int idx = tid; idx < 4096; idx += 256) {
        int r = idx >> 7, k = idx & 127;
        Vl[r][k] = Vinv[(size_t)bh * 16384 + (size_t)(r0 + r) * NL + k];
    }
    __syncthreads();
    int d = tid & 63, rg = tid >> 6;
    float acc[8] = {};
    for (int k = 0; k < NL; ++k) {
        float av = Ash[k][d];
#pragma unroll
        for (int i = 0; i < 8; ++i) acc[i] += Vl[rg * 8 + i][k] * av;
    }
#pragma unroll
    for (int i = 0; i < 8; ++i)
        W[(size_t)bh * 8192 + (size_t)(r0 + rg * 8 + i) * HD + d] = acc[i];
}

// ---------------- 8. X = softmax(Qs @ Klm^T) @ W, bf16 MFMA ----------------
#define QP 72
#define WP 136
__global__ __launch_bounds__(256) void k1x_mfma(const float* __restrict__ Q, const float* __restrict__ M,
                                                const float* __restrict__ Klm, const float* __restrict__ W,
                                                float* __restrict__ out) {
    int bh = blockIdx.y, b = bh / NH, q0 = blockIdx.x * 64;
    int tid = threadIdx.x;
    int wave = tid >> 6, lane = tid & 63, quad = lane >> 4, l16 = lane & 15;
    __shared__ ushort_t Qsh[64 * QP];
    __shared__ ushort_t Bsh[128 * QP];   // Klm tile; reused for P (64*WP=8704 <= 9216)
    __shared__ ushort_t Wt[64 * WP];     // W^T bf16 [d][lm^sw]
    const float4* Qg = (const float4*)(Q + ((size_t)bh * SQ + q0) * HD);
#pragma unroll
    for (int rep = 0; rep < 4; ++rep) {
        int idx = rep * 256 + tid;       // 1024 float4 = 64 rows x 16
        int r = idx >> 4, d4 = (idx & 15) * 4;
        float4 x = Qg[idx];
        float mm = M[b * SQ + q0 + r] * SCALE;
        *(uint2*)&Qsh[r * QP + d4] = make_uint2(pack2(x.x * mm, x.y * mm), pack2(x.z * mm, x.w * mm));
    }
    const float4* Kg = (const float4*)(Klm + (size_t)bh * NL * HD);
#pragma unroll
    for (int rep = 0; rep < 8; ++rep) {
        int idx = rep * 256 + tid;       // 2048 float4 = 128 rows x 16
        int r = idx >> 4, d4 = (idx & 15) * 4;
        float4 x = Kg[idx];
        *(uint2*)&Bsh[r * QP + d4] = make_uint2(pack2(x.x, x.y), pack2(x.z, x.w));
    }
    const float4* Wg = (const float4*)(W + (size_t)bh * NL * HD);
#pragma unroll
    for (int rep = 0; rep < 8; ++rep) {
        int idx = rep * 256 + tid;       // 2048 float4 = 128 lm x 16
        int lm = idx >> 4, d4 = (idx & 15) * 4;
        float4 x = Wg[idx];
        int sw = ((d4 >> 2) & 7) << 3;   // same for d4..d4+3
        Wt[(d4 + 0) * WP + (lm ^ sw)] = f2bf(x.x);
        Wt[(d4 + 1) * WP + (lm ^ sw)] = f2bf(x.y);
        Wt[(d4 + 2) * WP + (lm ^ sw)] = f2bf(x.z);
        Wt[(d4 + 3) * WP + (lm ^ sw)] = f2bf(x.w);
    }
    __syncthreads();
    int R = wave * 16;
    s16x8 aq[2];
#pragma unroll
    for (int ks = 0; ks < 2; ++ks) aq[ks] = ld_frag(&Qsh[(R + l16) * QP + ks * 32 + quad * 8]);
    f32x4 acc[8];
#pragma unroll
    for (int nt = 0; nt < 8; ++nt) acc[nt] = (f32x4){0.f, 0.f, 0.f, 0.f};
#pragma unroll
    for (int nt = 0; nt < 8; ++nt)
#pragma unroll
        for (int ks = 0; ks < 2; ++ks) {
            s16x8 bf = ld_frag(&Bsh[(nt * 16 + l16) * QP + ks * 32 + quad * 8]);
            acc[nt] = MFMA16(aq[ks], bf, acc[nt]);
        }
    float mx[4];
#pragma unroll
    for (int r = 0; r < 4; ++r) {
        mx[r] = acc[0][r];
#pragma unroll
        for (int nt = 1; nt < 8; ++nt) mx[r] = fmaxf(mx[r], acc[nt][r]);
    }
#pragma unroll
    for (int off = 1; off < 16; off <<= 1)
#pragma unroll
        for (int r = 0; r < 4; ++r) mx[r] = fmaxf(mx[r], __shfl_xor(mx[r], off));
    float ps[4] = {0.f, 0.f, 0.f, 0.f};
#pragma unroll
    for (int nt = 0; nt < 8; ++nt)
#pragma unroll
        for (int r = 0; r < 4; ++r) {
            float p = __expf(acc[nt][r] - mx[r]);
            acc[nt][r] = p;
            ps[r] += p;
        }
#pragma unroll
    for (int off = 1; off < 16; off <<= 1)
#pragma unroll
        for (int r = 0; r < 4; ++r) ps[r] += __shfl_xor(ps[r], off);
    float inv[4];
#pragma unroll
    for (int r = 0; r < 4; ++r) inv[r] = 1.f / ps[r];
    __syncthreads();                     // all waves done reading Bsh (Klm)
    ushort_t* Psh = Bsh;
    int psw = ((wave * 4 + quad) & 7) << 3;        // row = R+quad*4+r
    int asw = ((wave * 4 + (l16 >> 2)) & 7) << 3;  // row = R+l16
#pragma unroll
    for (int nt = 0; nt < 8; ++nt)
#pragma unroll
        for (int r = 0; r < 4; ++r)
            Psh[(R + quad * 4 + r) * WP + ((nt * 16 + l16) ^ psw)] = f2bf(acc[nt][r] * inv[r]);
    // PV: each wave reads only its own P rows -> no extra barrier (lgkmcnt orders within wave)
    f32x4 o[4];
#pragma unroll
    for (int dn = 0; dn < 4; ++dn) o[dn] = (f32x4){0.f, 0.f, 0.f, 0.f};
#pragma unroll
    for (int dn = 0; dn < 4; ++dn)
#pragma unroll
        for (int ks = 0; ks < 4; ++ks) {
            s16x8 af = ld_frag(&Psh[(R + l16) * WP + ((ks * 32 + quad * 8) ^ asw)]);
            int vrow = dn * 16 + l16;
            int wsw = ((vrow >> 2) & 7) << 3;
            s16x8 bf = ld_frag(&Wt[vrow * WP + ((ks * 32 + quad * 8) ^ wsw)]);
            o[dn] = MFMA16(af, bf, o[dn]);
        }
    float* op = out + ((size_t)bh * SQ + q0) * HD;
#pragma unroll
    for (int dn = 0; dn < 4; ++dn)
#pragma unroll
        for (int r = 0; r < 4; ++r)
            op[(R + quad * 4 + r) * HD + dn * 16 + l16] = o[dn][r];
}

extern "C" void kernel_launch(void* const* d_in, const int* in_sizes, int n_in,
                              void* d_out, int out_size, void* d_ws, size_t ws_size,
                              hipStream_t stream) {
    const float* Q = (const float*)d_in[0];
    const float* K = (const float*)d_in[1];
    const float* V = (const float*)d_in[2];
    const float* M = (const float*)d_in[3];
    float* out = (float*)d_out;

    float* ws  = (float*)d_ws;
    float* Qlm = ws;                 // 48*128*64
    float* Klm = Qlm + 393216;
    float* K2  = Klm + 393216;       // 48*128*128
    float* Vm0 = K2  + 786432;
    float* Vm1 = Vm0 + 786432;
    float* KV  = Vm1 + 786432;
    float* T1  = KV  + 786432;
    float* T2  = T1  + 786432;
    float* Ab  = T2  + 786432;       // 48*128*64
    float* Wb  = Ab  + 393216;
    uint_t* scal  = (uint_t*)(Wb + 393216);
    float* Mpart = Wb + 393216 + 16;     // 48*16*128
    float* Lpart = Mpart + 98304;
    float* Opart = Lpart + 98304;        // 48*16*128*64 = 6291456 floats

    lm_kernel<<<dim3(1536, 2), 256, 0, stream>>>(Q, K, M, Qlm, Klm, scal);
    k2_kernel<<<6144, 128, 0, stream>>>(Qlm, Klm, K2);
    colmax_kernel<<<48, 256, 0, stream>>>(K2, scal);
    initv_kernel<<<dim3(2, 2, 48), 256, 0, stream>>>(K2, scal, Vm0);

    float* Vc = Vm0; float* Vn = Vm1;
    for (int it = 0; it < 6; ++it) {
        if (it < 5) {   // split-bf16 MFMA iterations (noise contracted by final fp32 pass)
            nw_mfma<<<dim3(2, 48), 512, 0, stream>>>(K2, Vc, KV, 1.f, 0.f, 0);
            nw_mfma<<<dim3(2, 48), 512, 0, stream>>>(KV, KV, T1, 1.f, 7.f, 1);
            nw_mfma<<<dim3(2, 48), 512, 0, stream>>>(KV, T1, T2, 1.f, 15.f, 1);
            nw_mfma<<<dim3(2, 48), 512, 0, stream>>>(Vc, T2, Vn, 0.25f, 13.f, 1);
        } else {        // final iteration in pure fp32
            nw_matmul<<<dim3(4, 48), 512, 0, stream>>>(K2, Vc, KV, 1.f, 0.f, 0);
            nw_matmul<<<dim3(4, 48), 512, 0, stream>>>(KV, KV, T1, 1.f, 7.f, 1);
            nw_matmul<<<dim3(4, 48), 512, 0, stream>>>(KV, T1, T2, 1.f, 15.f, 1);
            nw_matmul<<<dim3(4, 48), 512, 0, stream>>>(Vc, T2, Vn, 0.25f, 13.f, 1);
        }
        float* t = Vc; Vc = Vn; Vn = t;
    }
    // after 6 iterations Vc == Vm0

    k3v_mfma<<<dim3(NCK, 48), 512, 0, stream>>>(K, V, M, Qlm, Opart, Mpart, Lpart);
    k3c_kernel<<<dim3(2, 48), 256, 0, stream>>>(Opart, Mpart, Lpart, Ab);
    w_kernel<<<dim3(4, 48), 256, 0, stream>>>(Vm0, Ab, Wb);
    k1x_mfma<<<dim3(64, 48), 256, 0, stream>>>(Q, M, Klm, Wb, out);
}

// Round 7
// 351.279 us; speedup vs baseline: 1.7044x; 1.2434x over previous
//
#include <hip/hip_runtime.h>

// NystromAttention on MI355X. fp32 I/O, bf16 MFMA for the two big attention
// matmuls (k3v flash + k1x). Newton chain: init + iterations 0-4 fused into ONE
// LDS-resident bf16-MFMA kernel (1 block/bh, 128 KiB LDS, __syncthreads only);
// final iteration 5 in fp32 VALU repairs bf16 noise (E -> 0.75E^3 per step).
// grid.sync banned (~30us/sync on gfx950).

typedef unsigned int uint_t;
typedef unsigned short ushort_t;
typedef short s16x8 __attribute__((ext_vector_type(8)));
typedef float f32x4 __attribute__((ext_vector_type(4)));

#define NB 4
#define NH 12
#define BH 48
#define SQ 4096
#define HD 64
#define NL 128
#define SEG 32
#define SCALE 0.35355339059327379f
#define NEGBIG 1.0e9f

__device__ __forceinline__ ushort_t f2bf(float f) {
    uint_t u = __float_as_uint(f);
    u += 0x7FFFu + ((u >> 16) & 1u);   // RNE
    return (ushort_t)(u >> 16);
}
__device__ __forceinline__ float bf2f(ushort_t h) {
    return __uint_as_float((uint_t)h << 16);
}
__device__ __forceinline__ uint_t pack2(float a, float b) {
    return (uint_t)f2bf(a) | ((uint_t)f2bf(b) << 16);
}
__device__ __forceinline__ s16x8 ld_frag(const ushort_t* p) {
    return __builtin_bit_cast(s16x8, *(const uint4*)p);
}
#define MFMA16(a, b, c) __builtin_amdgcn_mfma_f32_16x16x32_bf16(a, b, c, 0, 0, 0)

// ---------------- 1. landmark means (Q_lm, K_lm), scale+mask folded ----------------
__global__ __launch_bounds__(256) void lm_kernel(const float* __restrict__ Q, const float* __restrict__ K,
                          const float* __restrict__ M,
                          float* __restrict__ Qlm, float* __restrict__ Klm,
                          uint_t* __restrict__ scal) {
    int g  = blockIdx.x;             // bh*32 + lgrp
    int bh = g >> 5;
    int l  = ((g & 31) << 2) + (threadIdx.x >> 6);
    int b  = bh / NH;
    const float* src = blockIdx.y ? K : Q;
    float* dst = blockIdx.y ? Klm : Qlm;
    int t = threadIdx.x & 63;
    int j0 = t >> 4, d4 = (t & 15) * 4;
    size_t base = ((size_t)bh * SQ + (size_t)l * SEG) * HD;
    int mbase = b * SQ + l * SEG;
    float4 acc = make_float4(0.f, 0.f, 0.f, 0.f);
#pragma unroll
    for (int j = j0; j < SEG; j += 4) {
        float4 v = *(const float4*)(src + base + (size_t)j * HD + d4);
        float m = M[mbase + j];
        acc.x += v.x * m; acc.y += v.y * m; acc.z += v.z * m; acc.w += v.w * m;
    }
    acc.x += __shfl_down(acc.x, 32); acc.y += __shfl_down(acc.y, 32);
    acc.z += __shfl_down(acc.z, 32); acc.w += __shfl_down(acc.w, 32);
    acc.x += __shfl_down(acc.x, 16); acc.y += __shfl_down(acc.y, 16);
    acc.z += __shfl_down(acc.z, 16); acc.w += __shfl_down(acc.w, 16);
    if (t < 16) {
        float s = SCALE / (float)SEG;
        *(float4*)(dst + ((size_t)bh * NL + l) * HD + t * 4) =
            make_float4(acc.x * s, acc.y * s, acc.z * s, acc.w * s);
    }
    if (g == 0 && blockIdx.y == 0 && threadIdx.x < 2) scal[threadIdx.x] = 0u;
}

// ---------------- 2. kernel_2 = softmax(Qlm @ Klm^T) ----------------
__global__ void k2_kernel(const float* __restrict__ Qlm, const float* __restrict__ Klm,
                          float* __restrict__ K2) {
    int bh = blockIdx.x >> 7;
    int c  = threadIdx.x;            // 128 threads = one column each
    int lane = c & 63, wv = c >> 6;
    __shared__ float q[HD];
    __shared__ float red2[4];
    if (c < HD) q[c] = Qlm[(size_t)blockIdx.x * HD + c];
    __syncthreads();
    const float* krow = Klm + ((size_t)bh * NL + c) * HD;
    float s = 0.f;
#pragma unroll
    for (int d = 0; d < HD; d += 4) {
        float4 kv = *(const float4*)(krow + d);
        s += q[d] * kv.x + q[d + 1] * kv.y + q[d + 2] * kv.z + q[d + 3] * kv.w;
    }
    float m = s;
#pragma unroll
    for (int off = 1; off < 64; off <<= 1) m = fmaxf(m, __shfl_xor(m, off));
    if (lane == 0) red2[wv] = m;
    __syncthreads();
    float mx = fmaxf(red2[0], red2[1]);
    float e = __expf(s - mx);
    float se = e;
#pragma unroll
    for (int off = 1; off < 64; off <<= 1) se += __shfl_xor(se, off);
    if (lane == 0) red2[2 + wv] = se;
    __syncthreads();
    float inv = 1.f / (red2[2] + red2[3]);
    K2[(size_t)blockIdx.x * NL + c] = e * inv;
}

// ---------------- 3. global max col-sum -> init_scale (rowsum term == 1) ----------------
__global__ void colmax_kernel(const float* __restrict__ K2, uint_t* __restrict__ scal) {
    int bh = blockIdx.x;
    int tid = threadIdx.x;           // 256
    int c = tid & 127, rh = tid >> 7;
    __shared__ float red[256];
    const float* base = K2 + (size_t)bh * NL * NL;
    float cs = 0.f;
    for (int r = rh * 64; r < rh * 64 + 64; ++r) cs += base[(size_t)r * NL + c];
    red[tid] = cs; __syncthreads();
    if (tid < 128) red[tid] += red[tid + 128];
    __syncthreads();
    for (int st = 64; st > 0; st >>= 1) { if (tid < st) red[tid] = fmaxf(red[tid], red[tid + st]); __syncthreads(); }
    if (tid == 0) atomicMax(&scal[0], __float_as_uint(red[0]));
}

// ---------------- 4. fused Newton: V0 init + iterations 0..4, one launch ----------------
// One block per bh, 512 threads, 4 x 32KB swizzled bf16 LDS buffers (128 KiB).
// Horner: X=K2@V; Y2=X@(7I-X); Y4=X@(15I-Y2); Vn=0.25*V@(13I-Y4).
// (beta*I - .) folded into output stores; K2 A-fragments live in registers.
#define SWZ(r, c) (((((r) << 7) | (c))) ^ (((r) & 7) << 3))

template<bool REGA, bool WROW, bool TRANS>
__device__ __forceinline__ void nw_step(const s16x8 k2f[2][4],
                                        const ushort_t* __restrict__ Ar,
                                        const ushort_t* __restrict__ Bc,
                                        ushort_t* __restrict__ Oc,
                                        ushort_t* __restrict__ Or,
                                        float beta, float alpha,
                                        int wr, int wc, int quad, int l16) {
    f32x4 acc[2][4];
#pragma unroll
    for (int rf = 0; rf < 2; ++rf)
#pragma unroll
        for (int cf = 0; cf < 4; ++cf) acc[rf][cf] = (f32x4){0.f, 0.f, 0.f, 0.f};
#pragma unroll
    for (int ks = 0; ks < 4; ++ks) {
        int kof = ks * 32 + quad * 8;
        s16x8 a0, a1;
        if (REGA) { a0 = k2f[0][ks]; a1 = k2f[1][ks]; }
        else {
            a0 = ld_frag(&Ar[SWZ(wr * 32 + l16, kof)]);
            a1 = ld_frag(&Ar[SWZ(wr * 32 + 16 + l16, kof)]);
        }
#pragma unroll
        for (int cf = 0; cf < 4; ++cf) {
            s16x8 bf = ld_frag(&Bc[SWZ(wc * 64 + cf * 16 + l16, kof)]);
            acc[0][cf] = MFMA16(a0, bf, acc[0][cf]);
            acc[1][cf] = MFMA16(a1, bf, acc[1][cf]);
        }
    }
#pragma unroll
    for (int rf = 0; rf < 2; ++rf)
#pragma unroll
        for (int cf = 0; cf < 4; ++cf) {
            int col = wc * 64 + cf * 16 + l16;
            int rowb = wr * 32 + rf * 16 + quad * 4;
            ushort_t u[4];
#pragma unroll
            for (int i = 0; i < 4; ++i) {
                float v = acc[rf][cf][i];
                float oc = TRANS ? ((rowb + i == col ? beta : 0.f) - v) : (alpha * v);
                u[i] = f2bf(oc);
            }
            *(uint2*)&Oc[SWZ(col, rowb)] =
                make_uint2((uint_t)u[0] | ((uint_t)u[1] << 16), (uint_t)u[2] | ((uint_t)u[3] << 16));
            if (WROW) {
#pragma unroll
                for (int i = 0; i < 4; ++i)
                    Or[SWZ(rowb + i, col)] = f2bf(alpha * acc[rf][cf][i]);
            }
        }
}

__global__ __launch_bounds__(512) void newton_fused(const float* __restrict__ K2g,
                                                    const uint_t* __restrict__ scal,
                                                    float* __restrict__ Vout) {
    __shared__ ushort_t S0[16384];   // V_row / X_row (ping-pong)
    __shared__ ushort_t S1[16384];   // V_colT -> Y2_colT -> Vn_colT
    __shared__ ushort_t S2[16384];   // X_row / V_row (ping-pong)
    __shared__ ushort_t S3[16384];   // X_colT(7I-X) -> Y4_colT(13I-Y4)
    int bh = blockIdx.x;
    const float* Kb = K2g + (size_t)bh * NL * NL;
    int tid = threadIdx.x;
    int wave = tid >> 6, lane = tid & 63, quad = lane >> 4, l16 = lane & 15;
    int wr = wave & 3, wc = wave >> 2;          // wave tile rows [wr*32,+32), cols [wc*64,+64)
    float sc = 1.f / __uint_as_float(scal[0]);

    // preload K2 A-fragments for this wave's rows (constant across iterations)
    s16x8 k2f[2][4];
#pragma unroll
    for (int rf = 0; rf < 2; ++rf)
#pragma unroll
        for (int ks = 0; ks < 4; ++ks) {
            const float* p = Kb + (size_t)(wr * 32 + rf * 16 + l16) * NL + ks * 32 + quad * 8;
            float4 q0 = *(const float4*)p;
            float4 q1 = *(const float4*)(p + 4);
            k2f[rf][ks] = __builtin_bit_cast(s16x8,
                make_uint4(pack2(q0.x, q0.y), pack2(q0.z, q0.w), pack2(q1.x, q1.y), pack2(q1.z, q1.w)));
        }
    // init V0 = sc*K2^T:  V_colT[c][k] = sc*K2[c][k] (stream rows)
#pragma unroll
    for (int rep = 0; rep < 8; ++rep) {
        int idx = rep * 512 + tid;           // 4096 float4
        int c = idx >> 5, k4 = (idx & 31) * 4;
        float4 v = *(const float4*)(Kb + (size_t)c * NL + k4);
        ushort_t u0 = f2bf(sc * v.x), u1 = f2bf(sc * v.y), u2 = f2bf(sc * v.z), u3 = f2bf(sc * v.w);
        *(uint2*)&S1[SWZ(c, k4)] =
            make_uint2((uint_t)u0 | ((uint_t)u1 << 16), (uint_t)u2 | ((uint_t)u3 << 16));
    }
    // V_row[r][c] = sc*K2[c][r] (coalesced read, scattered b16 store)
#pragma unroll
    for (int rep = 0; rep < 8; ++rep) {
        int idx = rep * 512 + tid;
        int c = idx >> 5, r4 = (idx & 31) * 4;
        float4 v = *(const float4*)(Kb + (size_t)c * NL + r4);
        S0[SWZ(r4 + 0, c)] = f2bf(sc * v.x);
        S0[SWZ(r4 + 1, c)] = f2bf(sc * v.y);
        S0[SWZ(r4 + 2, c)] = f2bf(sc * v.z);
        S0[SWZ(r4 + 3, c)] = f2bf(sc * v.w);
    }
    __syncthreads();

    ushort_t* Vr = S0; ushort_t* Xr = S2;
    for (int it = 0; it < 5; ++it) {
        // X = K2 @ V : write X_row raw + S3 = (7I - X)^T
        nw_step<true, true, true>(k2f, nullptr, S1, S3, Xr, 7.f, 1.f, wr, wc, quad, l16);
        __syncthreads();
        // Y2 = X @ (7I-X) : write S1 = (15I - Y2)^T
        nw_step<false, false, true>(k2f, Xr, S3, S1, nullptr, 15.f, 1.f, wr, wc, quad, l16);
        __syncthreads();
        // Y4 = X @ (15I-Y2) : write S3 = (13I - Y4)^T
        nw_step<false, false, true>(k2f, Xr, S1, S3, nullptr, 13.f, 1.f, wr, wc, quad, l16);
        __syncthreads();
        // Vn = 0.25 * V @ (13I-Y4) : write Vn_row -> Xr slot, Vn_colT -> S1 (raw, scaled)
        nw_step<false, true, false>(k2f, Vr, S3, S1, Xr, 0.f, 0.25f, wr, wc, quad, l16);
        ushort_t* t = Vr; Vr = Xr; Xr = t;
        __syncthreads();
    }
    // write V5 (bf16 -> fp32) row-major
#pragma unroll
    for (int rep = 0; rep < 32; ++rep) {
        int idx = rep * 512 + tid;
        int r = idx >> 7, c = idx & 127;
        Vout[(size_t)bh * 16384 + idx] = bf2f(Vr[SWZ(r, c)]);
    }
}

// ---------------- 5. fp32 Newton matmul (final iteration) ----------------
__global__ __launch_bounds__(512) void nw_matmul(const float* __restrict__ A, const float* __restrict__ B,
                                                 float* __restrict__ C, float alpha, float beta, int mode) {
    int bh = blockIdx.y;
    int r0 = blockIdx.x * 32;
    const float* Ab = A + (size_t)bh * NL * NL;
    const float* Bb = B + (size_t)bh * NL * NL;
    float* Cb = C + (size_t)bh * NL * NL;
    __shared__ float Bs[NL][NL];     // 64 KB
    __shared__ float As[32][132];    // row-major, 528B row stride (16B aligned)
    int tid = threadIdx.x;
    int tx = tid & 31, ty = tid >> 5;   // ty 0..15
#pragma unroll
    for (int rep = 0; rep < 8; ++rep) {
        int idx = rep * 512 + tid;       // 4096 float4 = full 128x128 B
        int kr = idx >> 5, c4 = (idx & 31) * 4;
        float4 v = *(const float4*)(Bb + (size_t)kr * NL + c4);
        if (mode) {
            v.x = (kr == c4 + 0 ? beta : 0.f) - v.x;
            v.y = (kr == c4 + 1 ? beta : 0.f) - v.y;
            v.z = (kr == c4 + 2 ? beta : 0.f) - v.z;
            v.w = (kr == c4 + 3 ? beta : 0.f) - v.w;
        }
        *(float4*)&Bs[kr][c4] = v;
    }
#pragma unroll
    for (int rep = 0; rep < 2; ++rep) {
        int idx = rep * 512 + tid;       // 1024 float4 = 32 rows x 128
        int r = idx >> 5, k4 = (idx & 31) * 4;
        float4 v = *(const float4*)(Ab + (size_t)(r0 + r) * NL + k4);
        *(float4*)&As[r][k4] = v;
    }
    __syncthreads();
    float acc[2][4] = {};
#pragma unroll 4
    for (int k = 0; k < NL; ++k) {
        float a0 = As[ty * 2 + 0][k];
        float a1 = As[ty * 2 + 1][k];
        float4 bb = *(const float4*)&Bs[k][tx * 4];
        acc[0][0] += a0 * bb.x; acc[0][1] += a0 * bb.y; acc[0][2] += a0 * bb.z; acc[0][3] += a0 * bb.w;
        acc[1][0] += a1 * bb.x; acc[1][1] += a1 * bb.y; acc[1][2] += a1 * bb.z; acc[1][3] += a1 * bb.w;
    }
#pragma unroll
    for (int i = 0; i < 2; ++i) {
        float4 o = make_float4(alpha * acc[i][0], alpha * acc[i][1],
                               alpha * acc[i][2], alpha * acc[i][3]);
        *(float4*)(Cb + (size_t)(r0 + ty * 2 + i) * NL + tx * 4) = o;
    }
}

// ---------------- 6a. k3v flash, bf16 MFMA, key-split partials ----------------
// grid (16,48): block = (key-chunk of 256, bh). 8 waves x 16 landmark rows = all 128 rows.
#define KT 64
#define NCK 16
#define KP 72            // padded LDS row stride in ushorts (144 B, 16B-aligned)
__global__ __launch_bounds__(512) void k3v_mfma(const float* __restrict__ K, const float* __restrict__ V,
                                                const float* __restrict__ M, const float* __restrict__ Qlm,
                                                float* __restrict__ Opart, float* __restrict__ Mpart,
                                                float* __restrict__ Lpart) {
    int bh = blockIdx.y, b = bh / NH, ck = blockIdx.x;
    int tid = threadIdx.x;
    int wave = tid >> 6, lane = tid & 63, quad = lane >> 4, l16 = lane & 15;
    __shared__ ushort_t Ksh[KT * KP];          // [key][d] bf16
    __shared__ ushort_t Vsh[HD * KP];          // [d][key^sw] bf16 (transposed, swizzled)
    __shared__ ushort_t Psh[128 * KP];         // per-wave 16-row P regions, swizzled
    __shared__ float msc[KT], mbias[KT];
    int R0 = wave * 16;
    // preload Q A-fragments (constant across key tiles)
    s16x8 aq[2];
#pragma unroll
    for (int ks = 0; ks < 2; ++ks) {
        const float* qp = Qlm + ((size_t)bh * NL + R0 + l16) * HD + ks * 32 + quad * 8;
        float4 q0 = *(const float4*)qp;
        float4 q1 = *(const float4*)(qp + 4);
        aq[ks] = __builtin_bit_cast(s16x8,
            make_uint4(pack2(q0.x, q0.y), pack2(q0.z, q0.w), pack2(q1.x, q1.y), pack2(q1.z, q1.w)));
    }
    float m_run[4], l_run[4];
    f32x4 o[4];
#pragma unroll
    for (int r = 0; r < 4; ++r) { m_run[r] = -1e30f; l_run[r] = 0.f; }
#pragma unroll
    for (int dn = 0; dn < 4; ++dn) o[dn] = (f32x4){0.f, 0.f, 0.f, 0.f};

    const float4* Kg = (const float4*)(K + ((size_t)bh * SQ + ck * 256) * HD);
    const float4* Vg = (const float4*)(V + ((size_t)bh * SQ + ck * 256) * HD);
    const float* Mg = M + b * SQ + ck * 256;

    // prefetch tile 0 (2 float4 per array per thread)
    float4 kreg[2], vreg[2]; float mreg = 0.f;
#pragma unroll
    for (int rep = 0; rep < 2; ++rep) { int idx = rep * 512 + tid; kreg[rep] = Kg[idx]; vreg[rep] = Vg[idx]; }
    if (tid < KT) mreg = Mg[tid];

    int psw = ((wave * 4 + quad) & 7) << 3;           // Psh write-side swizzle (row = wave*16+quad*4+r)
    int asw = ((wave * 4 + (l16 >> 2)) & 7) << 3;     // Psh read-side swizzle (row = wave*16+l16)

    for (int t = 0; t < 4; ++t) {
        __syncthreads();
#pragma unroll
        for (int rep = 0; rep < 2; ++rep) {
            int idx = rep * 512 + tid;          // 1024 float4 = 64 keys x 16
            int key = idx >> 4, d4 = (idx & 15) * 4;
            float4 x = kreg[rep];
            *(uint2*)&Ksh[key * KP + d4] = make_uint2(pack2(x.x, x.y), pack2(x.z, x.w));
            float4 y = vreg[rep];
            int sw = ((d4 >> 2) & 7) << 3;      // same for d4..d4+3
            Vsh[(d4 + 0) * KP + (key ^ sw)] = f2bf(y.x);
            Vsh[(d4 + 1) * KP + (key ^ sw)] = f2bf(y.y);
            Vsh[(d4 + 2) * KP + (key ^ sw)] = f2bf(y.z);
            Vsh[(d4 + 3) * KP + (key ^ sw)] = f2bf(y.w);
        }
        if (tid < KT) {
            msc[tid] = mreg * SCALE;
            mbias[tid] = -NEGBIG * (1.f - mreg);
        }
        __syncthreads();
        if (t < 3) {        // issue next tile's loads; latency hides under compute
#pragma unroll
            for (int rep = 0; rep < 2; ++rep) {
                int idx = rep * 512 + tid;
                kreg[rep] = Kg[(t + 1) * 1024 + idx];
                vreg[rep] = Vg[(t + 1) * 1024 + idx];
            }
            if (tid < KT) mreg = Mg[(t + 1) * KT + tid];
        }
        // ---- QK^T ----
        f32x4 acc[4];
#pragma unroll
        for (int nt = 0; nt < 4; ++nt) acc[nt] = (f32x4){0.f, 0.f, 0.f, 0.f};
#pragma unroll
        for (int nt = 0; nt < 4; ++nt)
#pragma unroll
            for (int ks = 0; ks < 2; ++ks) {
                s16x8 bf = ld_frag(&Ksh[(nt * 16 + l16) * KP + ks * 32 + quad * 8]);
                acc[nt] = MFMA16(aq[ks], bf, acc[nt]);
            }
        float s[4][4];
#pragma unroll
        for (int nt = 0; nt < 4; ++nt) {
            float mm = msc[nt * 16 + l16], bb = mbias[nt * 16 + l16];
#pragma unroll
            for (int r = 0; r < 4; ++r) s[nt][r] = acc[nt][r] * mm + bb;
        }
        float mx[4];
#pragma unroll
        for (int r = 0; r < 4; ++r)
            mx[r] = fmaxf(fmaxf(s[0][r], s[1][r]), fmaxf(s[2][r], s[3][r]));
#pragma unroll
        for (int off = 1; off < 16; off <<= 1)
#pragma unroll
            for (int r = 0; r < 4; ++r) mx[r] = fmaxf(mx[r], __shfl_xor(mx[r], off));
        float al[4];
#pragma unroll
        for (int r = 0; r < 4; ++r) {
            float mn = fmaxf(m_run[r], mx[r]);
            al[r] = __expf(m_run[r] - mn);
            m_run[r] = mn;
        }
        float ps[4] = {0.f, 0.f, 0.f, 0.f};
        int prow = wave * 16;
#pragma unroll
        for (int nt = 0; nt < 4; ++nt)
#pragma unroll
            for (int r = 0; r < 4; ++r) {
                float p = __expf(s[nt][r] - m_run[r]);
                ps[r] += p;
                Psh[(prow + quad * 4 + r) * KP + ((nt * 16 + l16) ^ psw)] = f2bf(p);
            }
#pragma unroll
        for (int off = 1; off < 16; off <<= 1)
#pragma unroll
            for (int r = 0; r < 4; ++r) ps[r] += __shfl_xor(ps[r], off);
#pragma unroll
        for (int r = 0; r < 4; ++r) l_run[r] = l_run[r] * al[r] + ps[r];
#pragma unroll
        for (int dn = 0; dn < 4; ++dn)
#pragma unroll
            for (int r = 0; r < 4; ++r) o[dn][r] *= al[r];
        // ---- PV ----
#pragma unroll
        for (int dn = 0; dn < 4; ++dn)
#pragma unroll
            for (int ks = 0; ks < 2; ++ks) {
                s16x8 af = ld_frag(&Psh[(prow + l16) * KP + ((ks * 32 + quad * 8) ^ asw)]);
                int vrow = dn * 16 + l16;
                int vsw = ((vrow >> 2) & 7) << 3;
                s16x8 bf = ld_frag(&Vsh[vrow * KP + ((ks * 32 + quad * 8) ^ vsw)]);
                o[dn] = MFMA16(af, bf, o[dn]);
            }
    }
    size_t pbase = ((size_t)bh * NCK + ck) * NL;
#pragma unroll
    for (int dn = 0; dn < 4; ++dn)
#pragma unroll
        for (int r = 0; r < 4; ++r) {
            int row = R0 + quad * 4 + r;
            Opart[(pbase + row) * HD + dn * 16 + l16] = o[dn][r];
        }
    if (l16 == 0) {
#pragma unroll
        for (int r = 0; r < 4; ++r) {
            int row = R0 + quad * 4 + r;
            Mpart[pbase + row] = m_run[r];
            Lpart[pbase + row] = l_run[r];
        }
    }
}

// ---------------- 6b. combine key-split partials -> A ----------------
__global__ __launch_bounds__(256) void k3c_kernel(const float* __restrict__ Opart,
                                                  const float* __restrict__ Mpart,
                                                  const float* __restrict__ Lpart,
                                                  float* __restrict__ A) {
    int bh = blockIdx.y;
    int tid = threadIdx.x;
    int r = blockIdx.x * 64 + (tid >> 2);
    int dg = (tid & 3) * 16;
    size_t base = (size_t)bh * NCK * NL;
    float m[NCK], Mx = -1e30f;
#pragma unroll
    for (int ck = 0; ck < NCK; ++ck) { m[ck] = Mpart[base + ck * NL + r]; Mx = fmaxf(Mx, m[ck]); }
    float w[NCK], l = 0.f;
#pragma unroll
    for (int ck = 0; ck < NCK; ++ck) { w[ck] = __expf(m[ck] - Mx); l += w[ck] * Lpart[base + ck * NL + r]; }
    float inv = 1.f / l;
#pragma unroll
    for (int d4 = 0; d4 < 16; d4 += 4) {
        float4 acc = make_float4(0.f, 0.f, 0.f, 0.f);
#pragma unroll
        for (int ck = 0; ck < NCK; ++ck) {
            float4 v = *(const float4*)&Opart[(base + ck * NL + r) * HD + dg + d4];
            acc.x += w[ck] * v.x; acc.y += w[ck] * v.y; acc.z += w[ck] * v.z; acc.w += w[ck] * v.w;
        }
        acc.x *= inv; acc.y *= inv; acc.z *= inv; acc.w *= inv;
        *(float4*)&A[((size_t)bh * NL + r) * HD + dg + d4] = acc;
    }
}

// ---------------- 7. W = Vinv @ A ----------------
__global__ __launch_bounds__(256) void w_kernel(const float* __restrict__ Vinv, const float* __restrict__ A,
                                                float* __restrict__ W) {
    int bh = blockIdx.y;
    int r0 = blockIdx.x * 32;
    __shared__ float Ash[128][64];
    __shared__ float Vl[32][129];
    int tid = threadIdx.x;
    for (int idx = tid; idx < 8192; idx += 256) Ash[idx >> 6][idx & 63] = A[(size_t)bh * 8192 + idx];
    for (int idx = tid; idx < 4096; idx += 256) {
        int r = idx >> 7, k = idx & 127;
        Vl[r][k] = Vinv[(size_t)bh * 16384 + (size_t)(r0 + r) * NL + k];
    }
    __syncthreads();
    int d = tid & 63, rg = tid >> 6;
    float acc[8] = {};
    for (int k = 0; k < NL; ++k) {
        float av = Ash[k][d];
#pragma unroll
        for (int i = 0; i < 8; ++i) acc[i] += Vl[rg * 8 + i][k] * av;
    }
#pragma unroll
    for (int i = 0; i < 8; ++i)
        W[(size_t)bh * 8192 + (size_t)(r0 + rg * 8 + i) * HD + d] = acc[i];
}

// ---------------- 8. X = softmax(Qs @ Klm^T) @ W, bf16 MFMA ----------------
#define QP 72
#define WP 136
__global__ __launch_bounds__(256) void k1x_mfma(const float* __restrict__ Q, const float* __restrict__ M,
                                                const float* __restrict__ Klm, const float* __restrict__ W,
                                                float* __restrict__ out) {
    int bh = blockIdx.y, b = bh / NH, q0 = blockIdx.x * 64;
    int tid = threadIdx.x;
    int wave = tid >> 6, lane = tid & 63, quad = lane >> 4, l16 = lane & 15;
    __shared__ ushort_t Qsh[64 * QP];
    __shared__ ushort_t Bsh[128 * QP];   // Klm tile; reused for P (64*WP=8704 <= 9216)
    __shared__ ushort_t Wt[64 * WP];     // W^T bf16 [d][lm^sw]
    const float4* Qg = (const float4*)(Q + ((size_t)bh * SQ + q0) * HD);
#pragma unroll
    for (int rep = 0; rep < 4; ++rep) {
        int idx = rep * 256 + tid;       // 1024 float4 = 64 rows x 16
        int r = idx >> 4, d4 = (idx & 15) * 4;
        float4 x = Qg[idx];
        float mm = M[b * SQ + q0 + r] * SCALE;
        *(uint2*)&Qsh[r * QP + d4] = make_uint2(pack2(x.x * mm, x.y * mm), pack2(x.z * mm, x.w * mm));
    }
    const float4* Kg = (const float4*)(Klm + (size_t)bh * NL * HD);
#pragma unroll
    for (int rep = 0; rep < 8; ++rep) {
        int idx = rep * 256 + tid;       // 2048 float4 = 128 rows x 16
        int r = idx >> 4, d4 = (idx & 15) * 4;
        float4 x = Kg[idx];
        *(uint2*)&Bsh[r * QP + d4] = make_uint2(pack2(x.x, x.y), pack2(x.z, x.w));
    }
    const float4* Wg = (const float4*)(W + (size_t)bh * NL * HD);
#pragma unroll
    for (int rep = 0; rep < 8; ++rep) {
        int idx = rep * 256 + tid;       // 2048 float4 = 128 lm x 16
        int lm = idx >> 4, d4 = (idx & 15) * 4;
        float4 x = Wg[idx];
        int sw = ((d4 >> 2) & 7) << 3;   // same for d4..d4+3
        Wt[(d4 + 0) * WP + (lm ^ sw)] = f2bf(x.x);
        Wt[(d4 + 1) * WP + (lm ^ sw)] = f2bf(x.y);
        Wt[(d4 + 2) * WP + (lm ^ sw)] = f2bf(x.z);
        Wt[(d4 + 3) * WP + (lm ^ sw)] = f2bf(x.w);
    }
    __syncthreads();
    int R = wave * 16;
    s16x8 aq[2];
#pragma unroll
    for (int ks = 0; ks < 2; ++ks) aq[ks] = ld_frag(&Qsh[(R + l16) * QP + ks * 32 + quad * 8]);
    f32x4 acc[8];
#pragma unroll
    for (int nt = 0; nt < 8; ++nt) acc[nt] = (f32x4){0.f, 0.f, 0.f, 0.f};
#pragma unroll
    for (int nt = 0; nt < 8; ++nt)
#pragma unroll
        for (int ks = 0; ks < 2; ++ks) {
            s16x8 bf = ld_frag(&Bsh[(nt * 16 + l16) * QP + ks * 32 + quad * 8]);
            acc[nt] = MFMA16(aq[ks], bf, acc[nt]);
        }
    float mx[4];
#pragma unroll
    for (int r = 0; r < 4; ++r) {
        mx[r] = acc[0][r];
#pragma unroll
        for (int nt = 1; nt < 8; ++nt) mx[r] = fmaxf(mx[r], acc[nt][r]);
    }
#pragma unroll
    for (int off = 1; off < 16; off <<= 1)
#pragma unroll
        for (int r = 0; r < 4; ++r) mx[r] = fmaxf(mx[r], __shfl_xor(mx[r], off));
    float ps[4] = {0.f, 0.f, 0.f, 0.f};
#pragma unroll
    for (int nt = 0; nt < 8; ++nt)
#pragma unroll
        for (int r = 0; r < 4; ++r) {
            float p = __expf(acc[nt][r] - mx[r]);
            acc[nt][r] = p;
            ps[r] += p;
        }
#pragma unroll
    for (int off = 1; off < 16; off <<= 1)
#pragma unroll
        for (int r = 0; r < 4; ++r) ps[r] += __shfl_xor(ps[r], off);
    float inv[4];
#pragma unroll
    for (int r = 0; r < 4; ++r) inv[r] = 1.f / ps[r];
    __syncthreads();                     // all waves done reading Bsh (Klm)
    ushort_t* Psh = Bsh;
    int psw = ((wave * 4 + quad) & 7) << 3;        // row = R+quad*4+r
    int asw = ((wave * 4 + (l16 >> 2)) & 7) << 3;  // row = R+l16
#pragma unroll
    for (int nt = 0; nt < 8; ++nt)
#pragma unroll
        for (int r = 0; r < 4; ++r)
            Psh[(R + quad * 4 + r) * WP + ((nt * 16 + l16) ^ psw)] = f2bf(acc[nt][r] * inv[r]);
    // PV: each wave reads only its own P rows -> no extra barrier (lgkmcnt orders within wave)
    f32x4 o[4];
#pragma unroll
    for (int dn = 0; dn < 4; ++dn) o[dn] = (f32x4){0.f, 0.f, 0.f, 0.f};
#pragma unroll
    for (int dn = 0; dn < 4; ++dn)
#pragma unroll
        for (int ks = 0; ks < 4; ++ks) {
            s16x8 af = ld_frag(&Psh[(R + l16) * WP + ((ks * 32 + quad * 8) ^ asw)]);
            int vrow = dn * 16 + l16;
            int wsw = ((vrow >> 2) & 7) << 3;
            s16x8 bf = ld_frag(&Wt[vrow * WP + ((ks * 32 + quad * 8) ^ wsw)]);
            o[dn] = MFMA16(af, bf, o[dn]);
        }
    float* op = out + ((size_t)bh * SQ + q0) * HD;
#pragma unroll
    for (int dn = 0; dn < 4; ++dn)
#pragma unroll
        for (int r = 0; r < 4; ++r)
            op[(R + quad * 4 + r) * HD + dn * 16 + l16] = o[dn][r];
}

extern "C" void kernel_launch(void* const* d_in, const int* in_sizes, int n_in,
                              void* d_out, int out_size, void* d_ws, size_t ws_size,
                              hipStream_t stream) {
    const float* Q = (const float*)d_in[0];
    const float* K = (const float*)d_in[1];
    const float* V = (const float*)d_in[2];
    const float* M = (const float*)d_in[3];
    float* out = (float*)d_out;

    float* ws  = (float*)d_ws;
    float* Qlm = ws;                 // 48*128*64
    float* Klm = Qlm + 393216;
    float* K2  = Klm + 393216;       // 48*128*128
    float* Vm0 = K2  + 786432;
    float* Vm1 = Vm0 + 786432;
    float* KV  = Vm1 + 786432;
    float* T1  = KV  + 786432;
    float* T2  = T1  + 786432;
    float* Ab  = T2  + 786432;       // 48*128*64
    float* Wb  = Ab  + 393216;
    uint_t* scal  = (uint_t*)(Wb + 393216);
    float* Mpart = Wb + 393216 + 16;     // 48*16*128
    float* Lpart = Mpart + 98304;
    float* Opart = Lpart + 98304;        // 48*16*128*64 = 6291456 floats

    lm_kernel<<<dim3(1536, 2), 256, 0, stream>>>(Q, K, M, Qlm, Klm, scal);
    k2_kernel<<<6144, 128, 0, stream>>>(Qlm, Klm, K2);
    colmax_kernel<<<48, 256, 0, stream>>>(K2, scal);

    // Newton: init + iterations 0..4 fused (bf16 MFMA, LDS-resident), iteration 5 fp32.
    newton_fused<<<48, 512, 0, stream>>>(K2, scal, Vm0);
    nw_matmul<<<dim3(4, 48), 512, 0, stream>>>(K2, Vm0, KV, 1.f, 0.f, 0);
    nw_matmul<<<dim3(4, 48), 512, 0, stream>>>(KV, KV, T1, 1.f, 7.f, 1);
    nw_matmul<<<dim3(4, 48), 512, 0, stream>>>(KV, T1, T2, 1.f, 15.f, 1);
    nw_matmul<<<dim3(4, 48), 512, 0, stream>>>(Vm0, T2, Vm1, 0.25f, 13.f, 1);
    // result (V6) in Vm1

    k3v_mfma<<<dim3(NCK, 48), 512, 0, stream>>>(K, V, M, Qlm, Opart, Mpart, Lpart);
    k3c_kernel<<<dim3(2, 48), 256, 0, stream>>>(Opart, Mpart, Lpart, Ab);
    w_kernel<<<dim3(4, 48), 256, 0, stream>>>(Vm1, Ab, Wb);
    k1x_mfma<<<dim3(64, 48), 256, 0, stream>>>(Q, M, Klm, Wb, out);
}